// Round 11
// baseline (252.820 us; speedup 1.0000x reference)
//
#include <hip/hip_runtime.h>
#include <stdint.h>

// ============================================================================
// Motion_Relation_Mining — bit-exact replication of the JAX (CPU) reference.
//
// FROZEN (verified passing R0-R10, absmax 0.0): all f32 op sequences,
// NAN_POLICY_A, FMA-tanh, sequential reduce orders, selection key
// (enc(value)<<32)|~idx i.e. (value desc, index asc).
//
// R2: two-stage reductions replaced contended global atomics.
// R3: k_corr parallelized (scratch -> LDS, logs 100-wide).
// R4 (FAILED): ballot match-any — unroll spilled enc[] to scratch.
// R8: block-wide bitwise threshold search — barrier convoy (97us).
// R9: wave-autonomous threshold search (shfl-only, zero barriers);
//     16-way lane-replicated hist sub-histograms.
// R10: pass/launch reduction. k_mag_all computes all 7 pairs per thread
//      (x read once: 235->134 MB, coalesced reads, swizzle moved to the
//      7 MB writes). k_topgraph fuses top64+merge+graph in one block per
//      (b,f) via LDS candidates (no cand/ccnt/top globals). k_hist_pass
//      writes non-atomic per-block partials; k_corr sums them (kills
//      k_hist_reduce, k_init, and all global atomics). 10 -> 6 kernels.
// ============================================================================

typedef unsigned int u32;
typedef unsigned long long u64;

// sizes
#define BB 4
#define TT 8
#define CC 16
#define HWN 65536              // H*W
#define NF 7
#define FRAME 1048576LL        // C*H*W
#define NELF 7340032.0f        // nf*C*H*W per batch (exact in f32)
#define NPAIR 28
#define SEG 65536

// ws layout (bytes)
#define WS_MM 0                // u32[24] final min/max (encoded)
#define WS_CORR 128            // float[4]
#define WS_MAG 16384           // float[28][65536]
// overlaid inside WS_MAG region — fully consumed before k_mag_all writes:
#define WS_MMPART (WS_MAG)            // u32[2048][6]  = 48 KiB
#define WS_HISTC  (WS_MAG + 65536)    // u32[2048][300] = 2.4 MiB (per-block partials)
#define WS_NEED (16384 + 28LL*65536*4)

__device__ __forceinline__ u32 encf(float f) {
  u32 u = __float_as_uint(f);
  return (u & 0x80000000u) ? ~u : (u | 0x80000000u);
}
__device__ __forceinline__ float decf(u32 e) {
  u32 u = (e & 0x80000000u) ? (e ^ 0x80000000u) : ~e;
  return __uint_as_float(u);
}

// ---- single pass over frames: per-batch min/max of x_t, x_t1, x_t*x_t1.
// float4 loads; min/max order-free; product elementwise -> exact.
__global__ void k_minmax_pass(const float* __restrict__ x, u32* __restrict__ part) {
  const int blk = blockIdx.x;            // 2048 blocks: 512 per batch
  const int b = blk >> 9;
  const long long w0 = (long long)(blk & 511) * 2048;
  const int tid = threadIdx.x;
  u32 mn0 = 0xFFFFFFFFu, mx0 = 0u, mn1 = 0xFFFFFFFFu, mx1 = 0u,
      mnp = 0xFFFFFFFFu, mxp = 0u;
  float4 pv0, pv1;
  for (int t = 0; t < 8; ++t) {
    const float4* fp = (const float4*)(x + ((long long)(b * TT + t)) * FRAME + w0);
    float4 v0 = fp[tid];
    float4 v1 = fp[tid + 256];
#define MM_COMP(vc, pc)                                                     \
    {                                                                       \
      u32 ev = encf(vc);                                                    \
      if (t < 7) { mn0 = min(mn0, ev); mx0 = max(mx0, ev); }                \
      if (t > 0) {                                                          \
        mn1 = min(mn1, ev); mx1 = max(mx1, ev);                             \
        u32 ep = encf(__fmul_rn(pc, vc));                                   \
        mnp = min(mnp, ep); mxp = max(mxp, ep);                             \
      }                                                                     \
    }
    MM_COMP(v0.x, pv0.x) MM_COMP(v0.y, pv0.y) MM_COMP(v0.z, pv0.z) MM_COMP(v0.w, pv0.w)
    MM_COMP(v1.x, pv1.x) MM_COMP(v1.y, pv1.y) MM_COMP(v1.z, pv1.z) MM_COMP(v1.w, pv1.w)
#undef MM_COMP
    pv0 = v0; pv1 = v1;
  }
  __shared__ u32 sm[6][256];
  sm[0][tid] = mn0; sm[1][tid] = mx0; sm[2][tid] = mn1;
  sm[3][tid] = mx1; sm[4][tid] = mnp; sm[5][tid] = mxp;
  __syncthreads();
  for (int st = 128; st > 0; st >>= 1) {
    if (tid < st) {
      sm[0][tid] = min(sm[0][tid], sm[0][tid + st]);
      sm[1][tid] = max(sm[1][tid], sm[1][tid + st]);
      sm[2][tid] = min(sm[2][tid], sm[2][tid + st]);
      sm[3][tid] = max(sm[3][tid], sm[3][tid + st]);
      sm[4][tid] = min(sm[4][tid], sm[4][tid + st]);
      sm[5][tid] = max(sm[5][tid], sm[5][tid + st]);
    }
    __syncthreads();
  }
  if (tid == 0) {
    u32* o = part + blk * 6;
    o[0] = sm[0][0]; o[1] = sm[1][0]; o[2] = sm[2][0];
    o[3] = sm[3][0]; o[4] = sm[4][0]; o[5] = sm[5][0];
  }
}

// 4 blocks (one per batch): reduce 512 partials -> mm[b*6..]
__global__ void k_mm_reduce(const u32* __restrict__ part, u32* __restrict__ mm) {
  const int b = blockIdx.x;
  const int tid = threadIdx.x;
  const u32* p0 = part + (b * 512 + tid) * 6;
  const u32* p1 = p0 + 256 * 6;
  __shared__ u32 sm[6][256];
  sm[0][tid] = min(p0[0], p1[0]); sm[1][tid] = max(p0[1], p1[1]);
  sm[2][tid] = min(p0[2], p1[2]); sm[3][tid] = max(p0[3], p1[3]);
  sm[4][tid] = min(p0[4], p1[4]); sm[5][tid] = max(p0[5], p1[5]);
  __syncthreads();
  for (int st = 128; st > 0; st >>= 1) {
    if (tid < st) {
      sm[0][tid] = min(sm[0][tid], sm[0][tid + st]);
      sm[1][tid] = max(sm[1][tid], sm[1][tid + st]);
      sm[2][tid] = min(sm[2][tid], sm[2][tid + st]);
      sm[3][tid] = max(sm[3][tid], sm[3][tid + st]);
      sm[4][tid] = min(sm[4][tid], sm[4][tid + st]);
      sm[5][tid] = max(sm[5][tid], sm[5][tid + st]);
    }
    __syncthreads();
  }
  if (tid == 0)
    for (int i = 0; i < 6; ++i) mm[b * 6 + i] = sm[i][0];
}

__device__ __forceinline__ int bin_of(float v, float vmin, float den) {
  float tt = __fsub_rn(v, vmin);
  float q = __fdiv_rn(tt, den);
  float z = __fmul_rn(q, 100.0f);
  z = fminf(fmaxf(z, 0.0f), 99.0f);
  return (int)z;
}

// ---- single pass over frames: 16-way lane-replicated LDS sub-histograms,
// flushed NON-atomically to this block's private 300-u32 partial (R10).
__global__ void k_hist_pass(const float* __restrict__ x, const u32* __restrict__ mm,
                            u32* __restrict__ histc) {
  __shared__ u32 h[300 * 16];            // h[bin*16 + (lane&15)]
  for (int i = threadIdx.x; i < 4800; i += 256) h[i] = 0u;
  __syncthreads();
  const int blk = blockIdx.x;
  const int b = blk >> 9;
  const long long w0 = (long long)(blk & 511) * 2048;
  const int tid = threadIdx.x;
  const int sub = tid & 15;
  float mn_t = decf(mm[6 * b + 0]), den_t = __fsub_rn(decf(mm[6 * b + 1]), decf(mm[6 * b + 0]));
  float mn_1 = decf(mm[6 * b + 2]), den_1 = __fsub_rn(decf(mm[6 * b + 3]), decf(mm[6 * b + 2]));
  float mn_p = decf(mm[6 * b + 4]), den_p = __fsub_rn(decf(mm[6 * b + 5]), decf(mm[6 * b + 4]));
  float prev[8];
  for (int t = 0; t < 8; ++t) {
    const float* fp = x + ((long long)(b * TT + t)) * FRAME + w0 + tid;
#pragma unroll
    for (int k = 0; k < 8; ++k) {
      float v = fp[k << 8];
      if (t < 7) atomicAdd(&h[bin_of(v, mn_t, den_t) * 16 + sub], 1u);
      if (t > 0) {
        atomicAdd(&h[(100 + bin_of(v, mn_1, den_1)) * 16 + sub], 1u);
        float p = __fmul_rn(prev[k], v);
        atomicAdd(&h[(200 + bin_of(p, mn_p, den_p)) * 16 + sub], 1u);
      }
      prev[k] = v;
    }
  }
  __syncthreads();
  u32* dst = histc + blk * 300;
  for (int i = threadIdx.x; i < 300; i += 256) {
    u32 s = 0;
#pragma unroll
    for (int c = 0; c < 16; ++c) s += h[i * 16 + c];
    dst[i] = s;                          // non-atomic private partial
  }
}

// Eigen/XLA fast-tanh rational interpolant (FMA form) — FROZEN
__device__ float tanh_emul(float a) {
  const float kClamp = 7.90531110763549805f;
  float xx = fminf(fmaxf(a, -kClamp), kClamp);
  float x2 = __fmul_rn(xx, xx);
  float p = __fmaf_rn(x2, -2.76076847742355e-16f, 2.00018790482477e-13f);
  p = __fmaf_rn(x2, p, -8.60467152213735e-11f);
  p = __fmaf_rn(x2, p, 5.12229709037114e-08f);
  p = __fmaf_rn(x2, p, 1.48572235717979e-05f);
  p = __fmaf_rn(x2, p, 6.37261928875436e-04f);
  p = __fmaf_rn(x2, p, 4.89352455891786e-03f);
  p = __fmul_rn(xx, p);
  float q = __fmaf_rn(x2, 1.19825839466702e-06f, 1.18534705686654e-04f);
  q = __fmaf_rn(x2, q, 2.26843463243900e-03f);
  q = __fmaf_rn(x2, q, 4.89352518554385e-03f);
  float r = __fdiv_rn(p, q);
  if (fabsf(a) < 0.0004f) r = a;
  return r;
}

// ---- per-batch: sum 512 partial histograms (exact ints), then mi/corr.
// Parallel per-bin terms, FROZEN sequential add chains on lane 0.
__global__ void __launch_bounds__(256) k_corr(const u32* __restrict__ histc,
                                              float* __restrict__ corr) {
  const int b = blockIdx.x;
  const int tid = threadIdx.x;
  __shared__ u32 shist[300];
  __shared__ float shx[100], shx1[100], sterm[100];
  __shared__ float ssum[3];
  for (int i = tid; i < 300; i += 256) {
    const u32* src = histc + (long long)(b * 512) * 300 + i;
    u32 s = 0;
    for (int c = 0; c < 512; ++c) s += src[c * 300];
    shist[i] = s;
  }
  __syncthreads();
  const u32* HX = shist;
  const u32* HX1 = shist + 100;
  const u32* HJ = shist + 200;
  if (tid < 100) {
    shx[tid] = __fdiv_rn((float)HX[tid], NELF);
    shx1[tid] = __fdiv_rn((float)HX1[tid], NELF);
  }
  __syncthreads();
  if (tid == 0) {
    float Sj = 0.0f;
    for (int i = 0; i < 100; ++i) Sj = __fadd_rn(Sj, (float)HJ[i]);
    float Sx = 0.0f, Sx1 = 0.0f;
    for (int i = 0; i < 100; ++i) Sx = __fadd_rn(Sx, shx[i]);
    for (int i = 0; i < 100; ++i) Sx1 = __fadd_rn(Sx1, shx1[i]);
    ssum[0] = Sj; ssum[1] = Sx; ssum[2] = Sx1;
  }
  __syncthreads();
  if (tid < 100) {
    float Sj = ssum[0], Sx = ssum[1], Sx1 = ssum[2];
    float pj = __fdiv_rn((float)HJ[tid], Sj);
    float px = __fdiv_rn(shx[tid], Sx);
    float px1 = __fdiv_rn(shx1[tid], Sx1);
    float la = (float)log((double)__fadd_rn(pj, 1e-10f));
    float lb = (float)log((double)__fadd_rn(__fmul_rn(px, px1), 1e-10f));
    sterm[tid] = __fmul_rn(pj, __fsub_rn(la, lb));
  }
  __syncthreads();
  if (tid == 0) {
    float mi = 0.0f;
    for (int i = 0; i < 100; ++i) mi = __fadd_rn(mi, sterm[i]);
    float lm = (float)log((double)mi);
    float th = tanh_emul(lm);
    float num = (float)exp(0.8);
    corr[b] = __fdiv_rn(num, th);
  }
}

// ---- mag for ALL 7 pairs per thread (R10): x read exactly once, coalesced
// (lane -> hw contiguous); the s-swizzle moves to the 7.3 MB writes.
// Each acc[f] chain keeps the FROZEN sequential order over c.
__global__ void k_mag_all(const float* __restrict__ x, const float* __restrict__ corr,
                          float* __restrict__ mag) {
  int gid = blockIdx.x * 256 + threadIdx.x;   // 0..262143 = (b, hw)
  int b = gid >> 16;
  int hw = gid & 65535;
  int row = hw >> 8, col = hw & 255;
  int g = (row >> 3) * 32 + (col >> 3);
  int s = g * 64 + (row & 7) * 8 + (col & 7);
  const float cb = corr[b];
  const float* xp = x + (long long)b * TT * FRAME + hw;
  float acc[7] = {0.f, 0.f, 0.f, 0.f, 0.f, 0.f, 0.f};
  for (int c = 0; c < CC; ++c) {
    float v[8];
#pragma unroll
    for (int t = 0; t < 8; ++t)
      v[t] = xp[(long long)(t * CC + c) << 16];
#pragma unroll
    for (int f = 0; f < 7; ++f)
      acc[f] = __fadd_rn(acc[f], __fadd_rn(__fsub_rn(v[f + 1], v[f]), cb));
  }
#pragma unroll
  for (int f = 0; f < 7; ++f)
    mag[(((long long)(b * NF + f)) << 16) + s] = acc[f];
}

// ---- fused top-64 + centers/cov/inv + maha + top-169 + graph (R10).
// One block per (b,f). Phase 1: each of 16 waves owns 4096 mag elements in
// registers, finds its own 64th-largest via 32-round bitwise threshold
// search (shfl-only), emits enc>=T candidates to LDS (superset proof: a
// global-top-64 member has <=63 greater globally, hence <=63 in its wave,
// hence >= wave-T). Phase 2: exact block-wide rank merge (keys unique) ->
// rank-ordered centers. Phases 3-5: FROZEN cov/inv/maha/radix-169/write.
__global__ void __launch_bounds__(1024) k_topgraph(const float* __restrict__ mag,
                                                   float* __restrict__ out) {
  const int bf = blockIdx.x;
  const int tid = threadIdx.x;
  const int lane = tid & 63;
  const int wid = tid >> 6;          // 0..15
  __shared__ u64 candk[2048];
  __shared__ u32 scnt;
  __shared__ float cy[64], cx[64];
  __shared__ float sinv[4];
  __shared__ u32 keys[4096];
  __shared__ u32 bins[256];
  __shared__ u32 tie[4096];
  __shared__ u32 scal[4];

  if (tid == 0) scnt = 0u;
  __syncthreads();

  // phase 1: wave-autonomous threshold search (FROZEN R9 logic)
  const int wbase_elem = wid * 4096;
  const float4* m4 = (const float4*)(mag + (long long)bf * SEG + wbase_elem);
  u32 e[64];
#pragma unroll
  for (int k = 0; k < 16; ++k) {
    float4 v = m4[k * 64 + lane];
    e[4 * k + 0] = encf(v.x); e[4 * k + 1] = encf(v.y);
    e[4 * k + 2] = encf(v.z); e[4 * k + 3] = encf(v.w);
  }
  u32 T = 0u;
  for (int bit = 31; bit >= 0; --bit) {
    u32 Tt = T | (1u << bit);
    u32 c = 0;
#pragma unroll
    for (int k = 0; k < 64; ++k) c += (e[k] >= Tt) ? 1u : 0u;
#pragma unroll
    for (int off = 1; off < 64; off <<= 1) c += __shfl_xor(c, off, 64);
    if (c >= 64u) T = Tt;
  }
  u32 mycnt = 0;
#pragma unroll
  for (int k = 0; k < 64; ++k) mycnt += (e[k] >= T) ? 1u : 0u;
  u32 wtot = mycnt;
#pragma unroll
  for (int off = 1; off < 64; off <<= 1) wtot += __shfl_xor(wtot, off, 64);
  u32 rbase = 0;
  if (lane == 0) rbase = atomicAdd(&scnt, wtot);
  rbase = __shfl(rbase, 0, 64);
  u32 run = rbase;
  const u64 below = (lane == 0) ? 0ull : (~0ull >> (64 - lane));
#pragma unroll
  for (int k = 0; k < 64; ++k) {
    bool cnd = (e[k] >= T);
    u64 mask = __ballot(cnd);
    if (cnd) {
      u32 off = run + (u32)__popcll(mask & below);
      if (off < 2048u) {
        int s = wbase_elem + (k >> 2) * 256 + lane * 4 + (k & 3);
        candk[off] = ((u64)e[k] << 32) | (u64)(0xFFFFFFFFu - (u32)s);
      }
    }
    run += (u32)__popcll(mask);
  }
  __syncthreads();

  // phase 2: exact rank merge -> rank-ordered centers (FROZEN key order)
  u32 n = scnt; if (n > 2048u) n = 2048u;
  for (u32 i = tid; i < n; i += 1024) {
    u64 mine = candk[i];
    int rank = 0;
    for (u32 j = 0; j < n; ++j) rank += (candk[j] > mine) ? 1 : 0;
    if (rank < 64) {
      int idx = (int)(0xFFFFFFFFu - (u32)(mine & 0xFFFFFFFFull));
      cy[rank] = (float)((idx >> 6) * 8 + 4);
      cx[rank] = (float)((idx & 63) * 8 + 4);
    }
  }
  __syncthreads();

  // phase 3: mean/cov/inv — FROZEN sequential chains on thread 0
  if (tid == 0) {
    float sy = 0.f, sx = 0.f;
    for (int r = 0; r < 64; ++r) sy = __fadd_rn(sy, cy[r]);
    for (int r = 0; r < 64; ++r) sx = __fadd_rn(sx, cx[r]);
    float my = __fdiv_rn(sy, 64.0f), mx = __fdiv_rn(sx, 64.0f);
    float c00 = 0.f, c01 = 0.f, c11 = 0.f;
    for (int r = 0; r < 64; ++r) {
      float dy = __fsub_rn(cy[r], my);
      float dx = __fsub_rn(cx[r], mx);
      c00 = __fadd_rn(c00, __fmul_rn(dy, dy));
      c01 = __fadd_rn(c01, __fmul_rn(dy, dx));
      c11 = __fadd_rn(c11, __fmul_rn(dx, dx));
    }
    c00 = __fdiv_rn(c00, 63.0f); c01 = __fdiv_rn(c01, 63.0f); c11 = __fdiv_rn(c11, 63.0f);
    c00 = __fadd_rn(c00, 1e-6f); c11 = __fadd_rn(c11, 1e-6f);
    double det = (double)c00 * (double)c11 - (double)c01 * (double)c01;
    sinv[0] = (float)((double)c11 / det);
    sinv[1] = (float)(-(double)c01 / det);
    sinv[2] = sinv[1];
    sinv[3] = (float)((double)c00 / det);
  }
  __syncthreads();

  // phase 4: maha keys + zero output — FROZEN arithmetic, order-independent
  float i00 = sinv[0], i01 = sinv[1], i10 = sinv[2], i11 = sinv[3];
  long long obase = (long long)bf * 4096;
  for (int ee = tid; ee < 4096; ee += 1024) {
    int q = ee >> 6, r = ee & 63;
    float d0 = __fsub_rn(cy[r], cy[q]);
    float d1 = __fsub_rn(cx[r], cx[q]);
    float v0 = __fadd_rn(__fadd_rn(0.0f, __fmul_rn(d0, i00)), __fmul_rn(d1, i10));
    float v1 = __fadd_rn(__fadd_rn(0.0f, __fmul_rn(d0, i01)), __fmul_rn(d1, i11));
    float p0 = __fmul_rn(v0, d0);
    float p1 = __fmul_rn(v1, d1);
    float s0 = __fsqrt_rn(p0);
    float s1 = __fsqrt_rn(p1);
    float mh = __fadd_rn(__fadd_rn(0.0f, s0), s1);
    u32 key;
    if (mh != mh) key = 0xFFFFFFFFu;   // NaN first (POLICY A, FROZEN)
    else key = encf(-mh);
    keys[ee] = key;
    out[obase + ee] = 0.0f;
  }
  __syncthreads();

  // phase 5: radix-select top-169 — FROZEN semantics, 1024-thread striding
  u32 prefix = 0u, need = 169u;
  for (int pass = 0; pass < 4; ++pass) {
    int shift = 24 - pass * 8;
    if (tid == 0) scal[2] = 0u;
    if (tid < 256) bins[tid] = 0u;
    __syncthreads();
    for (int k = 0; k < 4; ++k) {
      u32 ky = keys[tid + (k << 10)];
      bool ok = (pass == 0) || ((ky >> (shift + 8)) == (prefix >> (shift + 8)));
      if (ok) atomicAdd(&bins[(ky >> shift) & 0xFFu], 1u);
    }
    __syncthreads();
    if (tid == 0) {
      u32 cum = 0; int d = 255;
      for (; d >= 0; --d) {
        u32 c = bins[d];
        if (cum + c >= need) break;
        cum += c;
      }
      if (d < 0) d = 0;
      scal[0] = prefix | ((u32)d << shift);
      scal[1] = need - cum;
    }
    __syncthreads();
    prefix = scal[0]; need = scal[1];
    __syncthreads();
  }
  for (int k = 0; k < 4; ++k) {
    int ee = tid + (k << 10);
    u32 ky = keys[ee];
    if (ky > prefix) out[obase + ee] = 1.0f;
    else if (ky == prefix) {
      u32 p = atomicAdd(&scal[2], 1u);
      tie[p] = (u32)ee;
    }
  }
  __syncthreads();
  int tc = (int)scal[2];
  for (int i = tid; i < tc; i += 1024) {
    u32 ei = tie[i];
    int rank = 0;
    for (int j = 0; j < tc; ++j) rank += (tie[j] < ei);
    if (rank < (int)need) out[obase + ei] = 1.0f;
  }
}

extern "C" void kernel_launch(void* const* d_in, const int* in_sizes, int n_in,
                              void* d_out, int out_size, void* d_ws, size_t ws_size,
                              hipStream_t stream) {
  if (ws_size < (size_t)WS_NEED) return;
  const float* x = (const float*)d_in[0];
  float* out = (float*)d_out;
  char* ws = (char*)d_ws;
  u32* mm = (u32*)(ws + WS_MM);
  float* corr = (float*)(ws + WS_CORR);
  float* mag = (float*)(ws + WS_MAG);
  u32* mmpart = (u32*)(ws + WS_MMPART);   // overlaid on mag region
  u32* histc = (u32*)(ws + WS_HISTC);     // overlaid on mag region

  hipLaunchKernelGGL(k_minmax_pass, dim3(2048), dim3(256), 0, stream, x, mmpart);
  hipLaunchKernelGGL(k_mm_reduce, dim3(4), dim3(256), 0, stream, mmpart, mm);
  hipLaunchKernelGGL(k_hist_pass, dim3(2048), dim3(256), 0, stream, x, mm, histc);
  hipLaunchKernelGGL(k_corr, dim3(4), dim3(256), 0, stream, histc, corr);
  hipLaunchKernelGGL(k_mag_all, dim3(1024), dim3(256), 0, stream, x, corr, mag);
  hipLaunchKernelGGL(k_topgraph, dim3(28), dim3(1024), 0, stream, mag, out);
}

// Round 12
// 233.963 us; speedup vs baseline: 1.0806x; 1.0806x over previous
//
#include <hip/hip_runtime.h>
#include <stdint.h>

// ============================================================================
// Motion_Relation_Mining — bit-exact replication of the JAX (CPU) reference.
//
// FROZEN (verified passing R0-R11, absmax 0.0): all f32 op sequences,
// NAN_POLICY_A, FMA-tanh, sequential reduce orders, selection key
// (enc(value)<<32)|~idx i.e. (value desc, index asc).
//
// R2: two-stage reductions replaced contended global atomics.
// R3: k_corr parallelized (scratch -> LDS, logs 100-wide).
// R4 (FAILED): ballot match-any — unroll spilled enc[] to scratch.
// R8: block-wide bitwise threshold search — barrier convoy (97us).
// R9: wave-autonomous threshold search (shfl-only, zero barriers).
// R10: k_mag_all (x read once), non-atomic hist partials, fused corr.
// R11 (FAILED): fusing top64 search into the 28-block graph kernel
//      concentrated the spilled e[64] traffic on 28 CUs -> 129us.
//      Lesson: fuse only phases with matching parallelism.
// R12: top64 search -> 448 blocks x 1 wave (max spread, zero LDS/barriers,
//      fixed 128-slot candidate ranges + non-atomic counts, no atomics at
//      all); merge+graph fused at 28 blocks (both 28-shaped). k_corr
//      partial-sum gets 8-way ILP (exact integer sum, order-free).
// ============================================================================

typedef unsigned int u32;
typedef unsigned long long u64;

// sizes
#define BB 4
#define TT 8
#define CC 16
#define HWN 65536              // H*W
#define NF 7
#define FRAME 1048576LL        // C*H*W
#define NELF 7340032.0f        // nf*C*H*W per batch (exact in f32)
#define NPAIR 28
#define SEG 65536

// ws layout (bytes)
#define WS_MM 0                // u32[24] final min/max (encoded)
#define WS_CORR 128            // float[4]
#define WS_WCNT 144            // u32[28][16] per-wave candidate counts
#define WS_MAG 16384           // float[28][65536]
// overlaid inside WS_MAG region — fully consumed before k_mag_all writes:
#define WS_MMPART (WS_MAG)            // u32[2048][6]  = 48 KiB
#define WS_HISTC  (WS_MAG + 65536)    // u32[2048][300] = 2.4 MiB
#define WS_NEED (16384 + 28LL*65536*4)
// candidate buffer lives in d_out: per bf a private 16KB range of
// 16 waves x 128 u64 slots. k_merge_graph consumes it (into LDS) before
// overwriting the same range with the output zeros/ones.

__device__ __forceinline__ u32 encf(float f) {
  u32 u = __float_as_uint(f);
  return (u & 0x80000000u) ? ~u : (u | 0x80000000u);
}
__device__ __forceinline__ float decf(u32 e) {
  u32 u = (e & 0x80000000u) ? (e ^ 0x80000000u) : ~e;
  return __uint_as_float(u);
}

// ---- single pass over frames: per-batch min/max of x_t, x_t1, x_t*x_t1.
// float4 loads; min/max order-free; product elementwise -> exact.
__global__ void k_minmax_pass(const float* __restrict__ x, u32* __restrict__ part) {
  const int blk = blockIdx.x;            // 2048 blocks: 512 per batch
  const int b = blk >> 9;
  const long long w0 = (long long)(blk & 511) * 2048;
  const int tid = threadIdx.x;
  u32 mn0 = 0xFFFFFFFFu, mx0 = 0u, mn1 = 0xFFFFFFFFu, mx1 = 0u,
      mnp = 0xFFFFFFFFu, mxp = 0u;
  float4 pv0, pv1;
  for (int t = 0; t < 8; ++t) {
    const float4* fp = (const float4*)(x + ((long long)(b * TT + t)) * FRAME + w0);
    float4 v0 = fp[tid];
    float4 v1 = fp[tid + 256];
#define MM_COMP(vc, pc)                                                     \
    {                                                                       \
      u32 ev = encf(vc);                                                    \
      if (t < 7) { mn0 = min(mn0, ev); mx0 = max(mx0, ev); }                \
      if (t > 0) {                                                          \
        mn1 = min(mn1, ev); mx1 = max(mx1, ev);                             \
        u32 ep = encf(__fmul_rn(pc, vc));                                   \
        mnp = min(mnp, ep); mxp = max(mxp, ep);                             \
      }                                                                     \
    }
    MM_COMP(v0.x, pv0.x) MM_COMP(v0.y, pv0.y) MM_COMP(v0.z, pv0.z) MM_COMP(v0.w, pv0.w)
    MM_COMP(v1.x, pv1.x) MM_COMP(v1.y, pv1.y) MM_COMP(v1.z, pv1.z) MM_COMP(v1.w, pv1.w)
#undef MM_COMP
    pv0 = v0; pv1 = v1;
  }
  __shared__ u32 sm[6][256];
  sm[0][tid] = mn0; sm[1][tid] = mx0; sm[2][tid] = mn1;
  sm[3][tid] = mx1; sm[4][tid] = mnp; sm[5][tid] = mxp;
  __syncthreads();
  for (int st = 128; st > 0; st >>= 1) {
    if (tid < st) {
      sm[0][tid] = min(sm[0][tid], sm[0][tid + st]);
      sm[1][tid] = max(sm[1][tid], sm[1][tid + st]);
      sm[2][tid] = min(sm[2][tid], sm[2][tid + st]);
      sm[3][tid] = max(sm[3][tid], sm[3][tid + st]);
      sm[4][tid] = min(sm[4][tid], sm[4][tid + st]);
      sm[5][tid] = max(sm[5][tid], sm[5][tid + st]);
    }
    __syncthreads();
  }
  if (tid == 0) {
    u32* o = part + blk * 6;
    o[0] = sm[0][0]; o[1] = sm[1][0]; o[2] = sm[2][0];
    o[3] = sm[3][0]; o[4] = sm[4][0]; o[5] = sm[5][0];
  }
}

// 4 blocks (one per batch): reduce 512 partials -> mm[b*6..]
__global__ void k_mm_reduce(const u32* __restrict__ part, u32* __restrict__ mm) {
  const int b = blockIdx.x;
  const int tid = threadIdx.x;
  const u32* p0 = part + (b * 512 + tid) * 6;
  const u32* p1 = p0 + 256 * 6;
  __shared__ u32 sm[6][256];
  sm[0][tid] = min(p0[0], p1[0]); sm[1][tid] = max(p0[1], p1[1]);
  sm[2][tid] = min(p0[2], p1[2]); sm[3][tid] = max(p0[3], p1[3]);
  sm[4][tid] = min(p0[4], p1[4]); sm[5][tid] = max(p0[5], p1[5]);
  __syncthreads();
  for (int st = 128; st > 0; st >>= 1) {
    if (tid < st) {
      sm[0][tid] = min(sm[0][tid], sm[0][tid + st]);
      sm[1][tid] = max(sm[1][tid], sm[1][tid + st]);
      sm[2][tid] = min(sm[2][tid], sm[2][tid + st]);
      sm[3][tid] = max(sm[3][tid], sm[3][tid + st]);
      sm[4][tid] = min(sm[4][tid], sm[4][tid + st]);
      sm[5][tid] = max(sm[5][tid], sm[5][tid + st]);
    }
    __syncthreads();
  }
  if (tid == 0)
    for (int i = 0; i < 6; ++i) mm[b * 6 + i] = sm[i][0];
}

__device__ __forceinline__ int bin_of(float v, float vmin, float den) {
  float tt = __fsub_rn(v, vmin);
  float q = __fdiv_rn(tt, den);
  float z = __fmul_rn(q, 100.0f);
  z = fminf(fmaxf(z, 0.0f), 99.0f);
  return (int)z;
}

// ---- single pass over frames: 16-way lane-replicated LDS sub-histograms,
// flushed NON-atomically to this block's private 300-u32 partial.
__global__ void k_hist_pass(const float* __restrict__ x, const u32* __restrict__ mm,
                            u32* __restrict__ histc) {
  __shared__ u32 h[300 * 16];            // h[bin*16 + (lane&15)]
  for (int i = threadIdx.x; i < 4800; i += 256) h[i] = 0u;
  __syncthreads();
  const int blk = blockIdx.x;
  const int b = blk >> 9;
  const long long w0 = (long long)(blk & 511) * 2048;
  const int tid = threadIdx.x;
  const int sub = tid & 15;
  float mn_t = decf(mm[6 * b + 0]), den_t = __fsub_rn(decf(mm[6 * b + 1]), decf(mm[6 * b + 0]));
  float mn_1 = decf(mm[6 * b + 2]), den_1 = __fsub_rn(decf(mm[6 * b + 3]), decf(mm[6 * b + 2]));
  float mn_p = decf(mm[6 * b + 4]), den_p = __fsub_rn(decf(mm[6 * b + 5]), decf(mm[6 * b + 4]));
  float prev[8];
  for (int t = 0; t < 8; ++t) {
    const float* fp = x + ((long long)(b * TT + t)) * FRAME + w0 + tid;
#pragma unroll
    for (int k = 0; k < 8; ++k) {
      float v = fp[k << 8];
      if (t < 7) atomicAdd(&h[bin_of(v, mn_t, den_t) * 16 + sub], 1u);
      if (t > 0) {
        atomicAdd(&h[(100 + bin_of(v, mn_1, den_1)) * 16 + sub], 1u);
        float p = __fmul_rn(prev[k], v);
        atomicAdd(&h[(200 + bin_of(p, mn_p, den_p)) * 16 + sub], 1u);
      }
      prev[k] = v;
    }
  }
  __syncthreads();
  u32* dst = histc + blk * 300;
  for (int i = threadIdx.x; i < 300; i += 256) {
    u32 s = 0;
#pragma unroll
    for (int c = 0; c < 16; ++c) s += h[i * 16 + c];
    dst[i] = s;                          // non-atomic private partial
  }
}

// Eigen/XLA fast-tanh rational interpolant (FMA form) — FROZEN
__device__ float tanh_emul(float a) {
  const float kClamp = 7.90531110763549805f;
  float xx = fminf(fmaxf(a, -kClamp), kClamp);
  float x2 = __fmul_rn(xx, xx);
  float p = __fmaf_rn(x2, -2.76076847742355e-16f, 2.00018790482477e-13f);
  p = __fmaf_rn(x2, p, -8.60467152213735e-11f);
  p = __fmaf_rn(x2, p, 5.12229709037114e-08f);
  p = __fmaf_rn(x2, p, 1.48572235717979e-05f);
  p = __fmaf_rn(x2, p, 6.37261928875436e-04f);
  p = __fmaf_rn(x2, p, 4.89352455891786e-03f);
  p = __fmul_rn(xx, p);
  float q = __fmaf_rn(x2, 1.19825839466702e-06f, 1.18534705686654e-04f);
  q = __fmaf_rn(x2, q, 2.26843463243900e-03f);
  q = __fmaf_rn(x2, q, 4.89352518554385e-03f);
  float r = __fdiv_rn(p, q);
  if (fabsf(a) < 0.0004f) r = a;
  return r;
}

// ---- per-batch: sum 512 partial histograms (8-way ILP, exact ints, R12),
// then mi/corr with FROZEN sequential chains on thread 0.
__global__ void __launch_bounds__(256) k_corr(const u32* __restrict__ histc,
                                              float* __restrict__ corr) {
  const int b = blockIdx.x;
  const int tid = threadIdx.x;
  __shared__ u32 shist[300];
  __shared__ float shx[100], shx1[100], sterm[100];
  __shared__ float ssum[3];
  for (int i = tid; i < 300; i += 256) {
    const u32* src = histc + (long long)(b * 512) * 300 + i;
    u32 s0 = 0, s1 = 0, s2 = 0, s3 = 0, s4 = 0, s5 = 0, s6 = 0, s7 = 0;
    for (int c = 0; c < 512; c += 8) {   // 8 independent load chains (ILP)
      s0 += src[(c + 0) * 300]; s1 += src[(c + 1) * 300];
      s2 += src[(c + 2) * 300]; s3 += src[(c + 3) * 300];
      s4 += src[(c + 4) * 300]; s5 += src[(c + 5) * 300];
      s6 += src[(c + 6) * 300]; s7 += src[(c + 7) * 300];
    }
    shist[i] = ((s0 + s1) + (s2 + s3)) + ((s4 + s5) + (s6 + s7));
  }
  __syncthreads();
  const u32* HX = shist;
  const u32* HX1 = shist + 100;
  const u32* HJ = shist + 200;
  if (tid < 100) {
    shx[tid] = __fdiv_rn((float)HX[tid], NELF);
    shx1[tid] = __fdiv_rn((float)HX1[tid], NELF);
  }
  __syncthreads();
  if (tid == 0) {
    float Sj = 0.0f;
    for (int i = 0; i < 100; ++i) Sj = __fadd_rn(Sj, (float)HJ[i]);
    float Sx = 0.0f, Sx1 = 0.0f;
    for (int i = 0; i < 100; ++i) Sx = __fadd_rn(Sx, shx[i]);
    for (int i = 0; i < 100; ++i) Sx1 = __fadd_rn(Sx1, shx1[i]);
    ssum[0] = Sj; ssum[1] = Sx; ssum[2] = Sx1;
  }
  __syncthreads();
  if (tid < 100) {
    float Sj = ssum[0], Sx = ssum[1], Sx1 = ssum[2];
    float pj = __fdiv_rn((float)HJ[tid], Sj);
    float px = __fdiv_rn(shx[tid], Sx);
    float px1 = __fdiv_rn(shx1[tid], Sx1);
    float la = (float)log((double)__fadd_rn(pj, 1e-10f));
    float lb = (float)log((double)__fadd_rn(__fmul_rn(px, px1), 1e-10f));
    sterm[tid] = __fmul_rn(pj, __fsub_rn(la, lb));
  }
  __syncthreads();
  if (tid == 0) {
    float mi = 0.0f;
    for (int i = 0; i < 100; ++i) mi = __fadd_rn(mi, sterm[i]);
    float lm = (float)log((double)mi);
    float th = tanh_emul(lm);
    float num = (float)exp(0.8);
    corr[b] = __fdiv_rn(num, th);
  }
}

// ---- mag for ALL 7 pairs per thread: x read exactly once, coalesced;
// the s-swizzle moves to the 7.3 MB writes. FROZEN per-c sequential order.
__global__ void k_mag_all(const float* __restrict__ x, const float* __restrict__ corr,
                          float* __restrict__ mag) {
  int gid = blockIdx.x * 256 + threadIdx.x;   // 0..262143 = (b, hw)
  int b = gid >> 16;
  int hw = gid & 65535;
  int row = hw >> 8, col = hw & 255;
  int g = (row >> 3) * 32 + (col >> 3);
  int s = g * 64 + (row & 7) * 8 + (col & 7);
  const float cb = corr[b];
  const float* xp = x + (long long)b * TT * FRAME + hw;
  float acc[7] = {0.f, 0.f, 0.f, 0.f, 0.f, 0.f, 0.f};
  for (int c = 0; c < CC; ++c) {
    float v[8];
#pragma unroll
    for (int t = 0; t < 8; ++t)
      v[t] = xp[(long long)(t * CC + c) << 16];
#pragma unroll
    for (int f = 0; f < 7; ++f)
      acc[f] = __fadd_rn(acc[f], __fadd_rn(__fsub_rn(v[f + 1], v[f]), cb));
  }
#pragma unroll
  for (int f = 0; f < 7; ++f)
    mag[(((long long)(b * NF + f)) << 16) + s] = acc[f];
}

// ---- top-64 stage 1 (R12): 448 blocks x ONE WAVE. Each wave owns 4096 mag
// elements in registers, finds its own 64th-largest via 32-round bitwise
// threshold search (shfl-only, zero LDS, zero barriers, zero atomics), and
// writes enc>=T candidates to its PRIVATE 128-slot range + a count word.
// Superset proof: a global-top-64 member has <=63 greater globally, hence
// <=63 in its wave's subset, hence >= wave-T -> emitted.
__global__ void __launch_bounds__(64) k_top64_local(const float* __restrict__ mag,
                                                    u64* __restrict__ cand,
                                                    u32* __restrict__ wcnt) {
  const int blk = blockIdx.x;        // 448: 16 per bf
  const int bf = blk >> 4;
  const int wid = blk & 15;
  const int lane = threadIdx.x;
  const int wbase_elem = wid * 4096;
  const float4* m4 = (const float4*)(mag + (long long)bf * SEG + wbase_elem);

  u32 e[64];
#pragma unroll
  for (int k = 0; k < 16; ++k) {
    float4 v = m4[k * 64 + lane];
    e[4 * k + 0] = encf(v.x); e[4 * k + 1] = encf(v.y);
    e[4 * k + 2] = encf(v.z); e[4 * k + 3] = encf(v.w);
  }
  u32 T = 0u;
  for (int bit = 31; bit >= 0; --bit) {
    u32 Tt = T | (1u << bit);
    u32 c = 0;
#pragma unroll
    for (int k = 0; k < 64; ++k) c += (e[k] >= Tt) ? 1u : 0u;
#pragma unroll
    for (int off = 1; off < 64; off <<= 1) c += __shfl_xor(c, off, 64);
    if (c >= 64u) T = Tt;            // uniform across wave (full butterfly)
  }

  // ballot-compacted emission into private slots [bf*2048 + wid*128 ..]
  u64* dst = cand + (long long)bf * 2048 + wid * 128;
  u32 run = 0;
  const u64 below = (lane == 0) ? 0ull : (~0ull >> (64 - lane));
#pragma unroll
  for (int k = 0; k < 64; ++k) {
    bool cnd = (e[k] >= T);
    u64 mask = __ballot(cnd);
    if (cnd) {
      u32 off = run + (u32)__popcll(mask & below);
      if (off < 128u) {
        int s = wbase_elem + (k >> 2) * 256 + lane * 4 + (k & 3);
        dst[off] = ((u64)e[k] << 32) | (u64)(0xFFFFFFFFu - (u32)s);
      }
    }
    run += (u32)__popcll(mask);
  }
  if (lane == 0) wcnt[bf * 16 + wid] = (run < 128u) ? run : 128u;
}

// ---- fused merge + graph (28 blocks x 1024 — both phases are 28-shaped).
// Phase 2: compact per-wave candidate ranges into LDS, exact block-wide
// rank merge (keys unique) -> rank-ordered centers (FROZEN key order).
// Phases 3-5: FROZEN cov/inv/maha/radix-169/write.
// NOTE: reads its cand range (in d_out) fully into LDS before overwriting
// the same range with output zeros (barrier-ordered within the block).
__global__ void __launch_bounds__(1024) k_merge_graph(const u64* __restrict__ cand,
                                                      const u32* __restrict__ wcnt,
                                                      float* __restrict__ out) {
  const int bf = blockIdx.x;
  const int tid = threadIdx.x;
  __shared__ u64 candk[2048];
  __shared__ u32 wbase[17];
  __shared__ float cy[64], cx[64];
  __shared__ float sinv[4];
  __shared__ u32 keys[4096];
  __shared__ u32 bins[256];
  __shared__ u32 tie[4096];
  __shared__ u32 scal[4];

  if (tid == 0) {
    u32 acc = 0;
    for (int w = 0; w < 16; ++w) { wbase[w] = acc; acc += wcnt[bf * 16 + w]; }
    wbase[16] = acc;
  }
  __syncthreads();
  // compact candidates into LDS
  for (int w = 0; w < 16; ++w) {
    u32 cnt = wbase[w + 1] - wbase[w];
    for (u32 s = tid; s < cnt; s += 1024)
      candk[wbase[w] + s] = cand[(long long)bf * 2048 + w * 128 + s];
  }
  __syncthreads();
  u32 n = wbase[16];

  // exact rank merge -> rank-ordered centers
  for (u32 i = tid; i < n; i += 1024) {
    u64 mine = candk[i];
    int rank = 0;
    for (u32 j = 0; j < n; ++j) rank += (candk[j] > mine) ? 1 : 0;
    if (rank < 64) {
      int idx = (int)(0xFFFFFFFFu - (u32)(mine & 0xFFFFFFFFull));
      cy[rank] = (float)((idx >> 6) * 8 + 4);
      cx[rank] = (float)((idx & 63) * 8 + 4);
    }
  }
  __syncthreads();

  // mean/cov/inv — FROZEN sequential chains on thread 0
  if (tid == 0) {
    float sy = 0.f, sx = 0.f;
    for (int r = 0; r < 64; ++r) sy = __fadd_rn(sy, cy[r]);
    for (int r = 0; r < 64; ++r) sx = __fadd_rn(sx, cx[r]);
    float my = __fdiv_rn(sy, 64.0f), mx = __fdiv_rn(sx, 64.0f);
    float c00 = 0.f, c01 = 0.f, c11 = 0.f;
    for (int r = 0; r < 64; ++r) {
      float dy = __fsub_rn(cy[r], my);
      float dx = __fsub_rn(cx[r], mx);
      c00 = __fadd_rn(c00, __fmul_rn(dy, dy));
      c01 = __fadd_rn(c01, __fmul_rn(dy, dx));
      c11 = __fadd_rn(c11, __fmul_rn(dx, dx));
    }
    c00 = __fdiv_rn(c00, 63.0f); c01 = __fdiv_rn(c01, 63.0f); c11 = __fdiv_rn(c11, 63.0f);
    c00 = __fadd_rn(c00, 1e-6f); c11 = __fadd_rn(c11, 1e-6f);
    double det = (double)c00 * (double)c11 - (double)c01 * (double)c01;
    sinv[0] = (float)((double)c11 / det);
    sinv[1] = (float)(-(double)c01 / det);
    sinv[2] = sinv[1];
    sinv[3] = (float)((double)c00 / det);
  }
  __syncthreads();

  // maha keys + zero output — FROZEN arithmetic, order-independent
  float i00 = sinv[0], i01 = sinv[1], i10 = sinv[2], i11 = sinv[3];
  long long obase = (long long)bf * 4096;
  for (int ee = tid; ee < 4096; ee += 1024) {
    int q = ee >> 6, r = ee & 63;
    float d0 = __fsub_rn(cy[r], cy[q]);
    float d1 = __fsub_rn(cx[r], cx[q]);
    float v0 = __fadd_rn(__fadd_rn(0.0f, __fmul_rn(d0, i00)), __fmul_rn(d1, i10));
    float v1 = __fadd_rn(__fadd_rn(0.0f, __fmul_rn(d0, i01)), __fmul_rn(d1, i11));
    float p0 = __fmul_rn(v0, d0);
    float p1 = __fmul_rn(v1, d1);
    float s0 = __fsqrt_rn(p0);
    float s1 = __fsqrt_rn(p1);
    float mh = __fadd_rn(__fadd_rn(0.0f, s0), s1);
    u32 key;
    if (mh != mh) key = 0xFFFFFFFFu;   // NaN first (POLICY A, FROZEN)
    else key = encf(-mh);
    keys[ee] = key;
    out[obase + ee] = 0.0f;
  }
  __syncthreads();

  // radix-select top-169 — FROZEN semantics
  u32 prefix = 0u, need = 169u;
  for (int pass = 0; pass < 4; ++pass) {
    int shift = 24 - pass * 8;
    if (tid == 0) scal[2] = 0u;
    if (tid < 256) bins[tid] = 0u;
    __syncthreads();
    for (int k = 0; k < 4; ++k) {
      u32 ky = keys[tid + (k << 10)];
      bool ok = (pass == 0) || ((ky >> (shift + 8)) == (prefix >> (shift + 8)));
      if (ok) atomicAdd(&bins[(ky >> shift) & 0xFFu], 1u);
    }
    __syncthreads();
    if (tid == 0) {
      u32 cum = 0; int d = 255;
      for (; d >= 0; --d) {
        u32 c = bins[d];
        if (cum + c >= need) break;
        cum += c;
      }
      if (d < 0) d = 0;
      scal[0] = prefix | ((u32)d << shift);
      scal[1] = need - cum;
    }
    __syncthreads();
    prefix = scal[0]; need = scal[1];
    __syncthreads();
  }
  for (int k = 0; k < 4; ++k) {
    int ee = tid + (k << 10);
    u32 ky = keys[ee];
    if (ky > prefix) out[obase + ee] = 1.0f;
    else if (ky == prefix) {
      u32 p = atomicAdd(&scal[2], 1u);
      tie[p] = (u32)ee;
    }
  }
  __syncthreads();
  int tc = (int)scal[2];
  for (int i = tid; i < tc; i += 1024) {
    u32 ei = tie[i];
    int rank = 0;
    for (int j = 0; j < tc; ++j) rank += (tie[j] < ei);
    if (rank < (int)need) out[obase + ei] = 1.0f;
  }
}

extern "C" void kernel_launch(void* const* d_in, const int* in_sizes, int n_in,
                              void* d_out, int out_size, void* d_ws, size_t ws_size,
                              hipStream_t stream) {
  if (ws_size < (size_t)WS_NEED) return;
  const float* x = (const float*)d_in[0];
  float* out = (float*)d_out;
  char* ws = (char*)d_ws;
  u32* mm = (u32*)(ws + WS_MM);
  float* corr = (float*)(ws + WS_CORR);
  u32* wcnt = (u32*)(ws + WS_WCNT);
  float* mag = (float*)(ws + WS_MAG);
  u32* mmpart = (u32*)(ws + WS_MMPART);   // overlaid on mag region
  u32* histc = (u32*)(ws + WS_HISTC);     // overlaid on mag region
  u64* cand = (u64*)d_out;                // consumed by k_merge_graph

  hipLaunchKernelGGL(k_minmax_pass, dim3(2048), dim3(256), 0, stream, x, mmpart);
  hipLaunchKernelGGL(k_mm_reduce, dim3(4), dim3(256), 0, stream, mmpart, mm);
  hipLaunchKernelGGL(k_hist_pass, dim3(2048), dim3(256), 0, stream, x, mm, histc);
  hipLaunchKernelGGL(k_corr, dim3(4), dim3(256), 0, stream, histc, corr);
  hipLaunchKernelGGL(k_mag_all, dim3(1024), dim3(256), 0, stream, x, corr, mag);
  hipLaunchKernelGGL(k_top64_local, dim3(448), dim3(64), 0, stream, mag, cand, wcnt);
  hipLaunchKernelGGL(k_merge_graph, dim3(28), dim3(1024), 0, stream, cand, wcnt, out);
}

// Round 13
// 211.660 us; speedup vs baseline: 1.1945x; 1.1054x over previous
//
#include <hip/hip_runtime.h>
#include <stdint.h>

// ============================================================================
// Motion_Relation_Mining — bit-exact replication of the JAX (CPU) reference.
//
// FROZEN (verified passing R0-R12, absmax 0.0): all f32 op sequences,
// NAN_POLICY_A, FMA-tanh, sequential reduce orders, selection key
// (enc(value)<<32)|~idx i.e. (value desc, index asc).
//
// R2: two-stage reductions replaced contended global atomics.
// R3: k_corr parallelized (scratch -> LDS, logs 100-wide).
// R4 (FAILED): ballot match-any — unroll spilled enc[] to scratch.
// R8: block-wide bitwise threshold search — barrier convoy (97us).
// R9: wave-autonomous threshold search (shfl-only, zero barriers).
// R10: k_mag_all (x read once), non-atomic hist partials, fused corr.
// R11 (FAILED): fusing top64 into the 28-block kernel throttled it.
// R12: 448x64 top64 + 28-block merge_graph. merge_graph = 86us: radix-169
//      had (a) same-address LDS atomics on CLUSTERED maha keys (~4096-deep
//      serialization/pass, the R4 disease) and (b) a serial 256-bin scan on
//      thread 0 x4 passes (~123K dependent-latency cycles ~= 50us).
// R13: phase 5 fixed — 16-way lane-replicated bins (R9-proven) + parallel
//      suffix-inclusive scan (exact same d*/need by integer monotonicity).
// ============================================================================

typedef unsigned int u32;
typedef unsigned long long u64;

// sizes
#define BB 4
#define TT 8
#define CC 16
#define HWN 65536              // H*W
#define NF 7
#define FRAME 1048576LL        // C*H*W
#define NELF 7340032.0f        // nf*C*H*W per batch (exact in f32)
#define NPAIR 28
#define SEG 65536

// ws layout (bytes)
#define WS_MM 0                // u32[24] final min/max (encoded)
#define WS_CORR 128            // float[4]
#define WS_WCNT 144            // u32[28][16] per-wave candidate counts
#define WS_MAG 16384           // float[28][65536]
// overlaid inside WS_MAG region — fully consumed before k_mag_all writes:
#define WS_MMPART (WS_MAG)            // u32[2048][6]  = 48 KiB
#define WS_HISTC  (WS_MAG + 65536)    // u32[2048][300] = 2.4 MiB
#define WS_NEED (16384 + 28LL*65536*4)
// candidate buffer lives in d_out: per bf a private 16KB range of
// 16 waves x 128 u64 slots. k_merge_graph consumes it (into LDS) before
// overwriting the same range with the output zeros/ones.

__device__ __forceinline__ u32 encf(float f) {
  u32 u = __float_as_uint(f);
  return (u & 0x80000000u) ? ~u : (u | 0x80000000u);
}
__device__ __forceinline__ float decf(u32 e) {
  u32 u = (e & 0x80000000u) ? (e ^ 0x80000000u) : ~e;
  return __uint_as_float(u);
}

// ---- single pass over frames: per-batch min/max of x_t, x_t1, x_t*x_t1.
// float4 loads; min/max order-free; product elementwise -> exact.
__global__ void k_minmax_pass(const float* __restrict__ x, u32* __restrict__ part) {
  const int blk = blockIdx.x;            // 2048 blocks: 512 per batch
  const int b = blk >> 9;
  const long long w0 = (long long)(blk & 511) * 2048;
  const int tid = threadIdx.x;
  u32 mn0 = 0xFFFFFFFFu, mx0 = 0u, mn1 = 0xFFFFFFFFu, mx1 = 0u,
      mnp = 0xFFFFFFFFu, mxp = 0u;
  float4 pv0, pv1;
  for (int t = 0; t < 8; ++t) {
    const float4* fp = (const float4*)(x + ((long long)(b * TT + t)) * FRAME + w0);
    float4 v0 = fp[tid];
    float4 v1 = fp[tid + 256];
#define MM_COMP(vc, pc)                                                     \
    {                                                                       \
      u32 ev = encf(vc);                                                    \
      if (t < 7) { mn0 = min(mn0, ev); mx0 = max(mx0, ev); }                \
      if (t > 0) {                                                          \
        mn1 = min(mn1, ev); mx1 = max(mx1, ev);                             \
        u32 ep = encf(__fmul_rn(pc, vc));                                   \
        mnp = min(mnp, ep); mxp = max(mxp, ep);                             \
      }                                                                     \
    }
    MM_COMP(v0.x, pv0.x) MM_COMP(v0.y, pv0.y) MM_COMP(v0.z, pv0.z) MM_COMP(v0.w, pv0.w)
    MM_COMP(v1.x, pv1.x) MM_COMP(v1.y, pv1.y) MM_COMP(v1.z, pv1.z) MM_COMP(v1.w, pv1.w)
#undef MM_COMP
    pv0 = v0; pv1 = v1;
  }
  __shared__ u32 sm[6][256];
  sm[0][tid] = mn0; sm[1][tid] = mx0; sm[2][tid] = mn1;
  sm[3][tid] = mx1; sm[4][tid] = mnp; sm[5][tid] = mxp;
  __syncthreads();
  for (int st = 128; st > 0; st >>= 1) {
    if (tid < st) {
      sm[0][tid] = min(sm[0][tid], sm[0][tid + st]);
      sm[1][tid] = max(sm[1][tid], sm[1][tid + st]);
      sm[2][tid] = min(sm[2][tid], sm[2][tid + st]);
      sm[3][tid] = max(sm[3][tid], sm[3][tid + st]);
      sm[4][tid] = min(sm[4][tid], sm[4][tid + st]);
      sm[5][tid] = max(sm[5][tid], sm[5][tid + st]);
    }
    __syncthreads();
  }
  if (tid == 0) {
    u32* o = part + blk * 6;
    o[0] = sm[0][0]; o[1] = sm[1][0]; o[2] = sm[2][0];
    o[3] = sm[3][0]; o[4] = sm[4][0]; o[5] = sm[5][0];
  }
}

// 4 blocks (one per batch): reduce 512 partials -> mm[b*6..]
__global__ void k_mm_reduce(const u32* __restrict__ part, u32* __restrict__ mm) {
  const int b = blockIdx.x;
  const int tid = threadIdx.x;
  const u32* p0 = part + (b * 512 + tid) * 6;
  const u32* p1 = p0 + 256 * 6;
  __shared__ u32 sm[6][256];
  sm[0][tid] = min(p0[0], p1[0]); sm[1][tid] = max(p0[1], p1[1]);
  sm[2][tid] = min(p0[2], p1[2]); sm[3][tid] = max(p0[3], p1[3]);
  sm[4][tid] = min(p0[4], p1[4]); sm[5][tid] = max(p0[5], p1[5]);
  __syncthreads();
  for (int st = 128; st > 0; st >>= 1) {
    if (tid < st) {
      sm[0][tid] = min(sm[0][tid], sm[0][tid + st]);
      sm[1][tid] = max(sm[1][tid], sm[1][tid + st]);
      sm[2][tid] = min(sm[2][tid], sm[2][tid + st]);
      sm[3][tid] = max(sm[3][tid], sm[3][tid + st]);
      sm[4][tid] = min(sm[4][tid], sm[4][tid + st]);
      sm[5][tid] = max(sm[5][tid], sm[5][tid + st]);
    }
    __syncthreads();
  }
  if (tid == 0)
    for (int i = 0; i < 6; ++i) mm[b * 6 + i] = sm[i][0];
}

__device__ __forceinline__ int bin_of(float v, float vmin, float den) {
  float tt = __fsub_rn(v, vmin);
  float q = __fdiv_rn(tt, den);
  float z = __fmul_rn(q, 100.0f);
  z = fminf(fmaxf(z, 0.0f), 99.0f);
  return (int)z;
}

// ---- single pass over frames: 16-way lane-replicated LDS sub-histograms,
// flushed NON-atomically to this block's private 300-u32 partial.
__global__ void k_hist_pass(const float* __restrict__ x, const u32* __restrict__ mm,
                            u32* __restrict__ histc) {
  __shared__ u32 h[300 * 16];            // h[bin*16 + (lane&15)]
  for (int i = threadIdx.x; i < 4800; i += 256) h[i] = 0u;
  __syncthreads();
  const int blk = blockIdx.x;
  const int b = blk >> 9;
  const long long w0 = (long long)(blk & 511) * 2048;
  const int tid = threadIdx.x;
  const int sub = tid & 15;
  float mn_t = decf(mm[6 * b + 0]), den_t = __fsub_rn(decf(mm[6 * b + 1]), decf(mm[6 * b + 0]));
  float mn_1 = decf(mm[6 * b + 2]), den_1 = __fsub_rn(decf(mm[6 * b + 3]), decf(mm[6 * b + 2]));
  float mn_p = decf(mm[6 * b + 4]), den_p = __fsub_rn(decf(mm[6 * b + 5]), decf(mm[6 * b + 4]));
  float prev[8];
  for (int t = 0; t < 8; ++t) {
    const float* fp = x + ((long long)(b * TT + t)) * FRAME + w0 + tid;
#pragma unroll
    for (int k = 0; k < 8; ++k) {
      float v = fp[k << 8];
      if (t < 7) atomicAdd(&h[bin_of(v, mn_t, den_t) * 16 + sub], 1u);
      if (t > 0) {
        atomicAdd(&h[(100 + bin_of(v, mn_1, den_1)) * 16 + sub], 1u);
        float p = __fmul_rn(prev[k], v);
        atomicAdd(&h[(200 + bin_of(p, mn_p, den_p)) * 16 + sub], 1u);
      }
      prev[k] = v;
    }
  }
  __syncthreads();
  u32* dst = histc + blk * 300;
  for (int i = threadIdx.x; i < 300; i += 256) {
    u32 s = 0;
#pragma unroll
    for (int c = 0; c < 16; ++c) s += h[i * 16 + c];
    dst[i] = s;                          // non-atomic private partial
  }
}

// Eigen/XLA fast-tanh rational interpolant (FMA form) — FROZEN
__device__ float tanh_emul(float a) {
  const float kClamp = 7.90531110763549805f;
  float xx = fminf(fmaxf(a, -kClamp), kClamp);
  float x2 = __fmul_rn(xx, xx);
  float p = __fmaf_rn(x2, -2.76076847742355e-16f, 2.00018790482477e-13f);
  p = __fmaf_rn(x2, p, -8.60467152213735e-11f);
  p = __fmaf_rn(x2, p, 5.12229709037114e-08f);
  p = __fmaf_rn(x2, p, 1.48572235717979e-05f);
  p = __fmaf_rn(x2, p, 6.37261928875436e-04f);
  p = __fmaf_rn(x2, p, 4.89352455891786e-03f);
  p = __fmul_rn(xx, p);
  float q = __fmaf_rn(x2, 1.19825839466702e-06f, 1.18534705686654e-04f);
  q = __fmaf_rn(x2, q, 2.26843463243900e-03f);
  q = __fmaf_rn(x2, q, 4.89352518554385e-03f);
  float r = __fdiv_rn(p, q);
  if (fabsf(a) < 0.0004f) r = a;
  return r;
}

// ---- per-batch: sum 512 partial histograms (8-way ILP, exact ints),
// then mi/corr with FROZEN sequential chains on thread 0.
__global__ void __launch_bounds__(256) k_corr(const u32* __restrict__ histc,
                                              float* __restrict__ corr) {
  const int b = blockIdx.x;
  const int tid = threadIdx.x;
  __shared__ u32 shist[300];
  __shared__ float shx[100], shx1[100], sterm[100];
  __shared__ float ssum[3];
  for (int i = tid; i < 300; i += 256) {
    const u32* src = histc + (long long)(b * 512) * 300 + i;
    u32 s0 = 0, s1 = 0, s2 = 0, s3 = 0, s4 = 0, s5 = 0, s6 = 0, s7 = 0;
    for (int c = 0; c < 512; c += 8) {   // 8 independent load chains (ILP)
      s0 += src[(c + 0) * 300]; s1 += src[(c + 1) * 300];
      s2 += src[(c + 2) * 300]; s3 += src[(c + 3) * 300];
      s4 += src[(c + 4) * 300]; s5 += src[(c + 5) * 300];
      s6 += src[(c + 6) * 300]; s7 += src[(c + 7) * 300];
    }
    shist[i] = ((s0 + s1) + (s2 + s3)) + ((s4 + s5) + (s6 + s7));
  }
  __syncthreads();
  const u32* HX = shist;
  const u32* HX1 = shist + 100;
  const u32* HJ = shist + 200;
  if (tid < 100) {
    shx[tid] = __fdiv_rn((float)HX[tid], NELF);
    shx1[tid] = __fdiv_rn((float)HX1[tid], NELF);
  }
  __syncthreads();
  if (tid == 0) {
    float Sj = 0.0f;
    for (int i = 0; i < 100; ++i) Sj = __fadd_rn(Sj, (float)HJ[i]);
    float Sx = 0.0f, Sx1 = 0.0f;
    for (int i = 0; i < 100; ++i) Sx = __fadd_rn(Sx, shx[i]);
    for (int i = 0; i < 100; ++i) Sx1 = __fadd_rn(Sx1, shx1[i]);
    ssum[0] = Sj; ssum[1] = Sx; ssum[2] = Sx1;
  }
  __syncthreads();
  if (tid < 100) {
    float Sj = ssum[0], Sx = ssum[1], Sx1 = ssum[2];
    float pj = __fdiv_rn((float)HJ[tid], Sj);
    float px = __fdiv_rn(shx[tid], Sx);
    float px1 = __fdiv_rn(shx1[tid], Sx1);
    float la = (float)log((double)__fadd_rn(pj, 1e-10f));
    float lb = (float)log((double)__fadd_rn(__fmul_rn(px, px1), 1e-10f));
    sterm[tid] = __fmul_rn(pj, __fsub_rn(la, lb));
  }
  __syncthreads();
  if (tid == 0) {
    float mi = 0.0f;
    for (int i = 0; i < 100; ++i) mi = __fadd_rn(mi, sterm[i]);
    float lm = (float)log((double)mi);
    float th = tanh_emul(lm);
    float num = (float)exp(0.8);
    corr[b] = __fdiv_rn(num, th);
  }
}

// ---- mag for ALL 7 pairs per thread: x read exactly once, coalesced;
// the s-swizzle moves to the 7.3 MB writes. FROZEN per-c sequential order.
__global__ void k_mag_all(const float* __restrict__ x, const float* __restrict__ corr,
                          float* __restrict__ mag) {
  int gid = blockIdx.x * 256 + threadIdx.x;   // 0..262143 = (b, hw)
  int b = gid >> 16;
  int hw = gid & 65535;
  int row = hw >> 8, col = hw & 255;
  int g = (row >> 3) * 32 + (col >> 3);
  int s = g * 64 + (row & 7) * 8 + (col & 7);
  const float cb = corr[b];
  const float* xp = x + (long long)b * TT * FRAME + hw;
  float acc[7] = {0.f, 0.f, 0.f, 0.f, 0.f, 0.f, 0.f};
  for (int c = 0; c < CC; ++c) {
    float v[8];
#pragma unroll
    for (int t = 0; t < 8; ++t)
      v[t] = xp[(long long)(t * CC + c) << 16];
#pragma unroll
    for (int f = 0; f < 7; ++f)
      acc[f] = __fadd_rn(acc[f], __fadd_rn(__fsub_rn(v[f + 1], v[f]), cb));
  }
#pragma unroll
  for (int f = 0; f < 7; ++f)
    mag[(((long long)(b * NF + f)) << 16) + s] = acc[f];
}

// ---- top-64 stage 1: 448 blocks x ONE WAVE. Each wave owns 4096 mag
// elements in registers, finds its own 64th-largest via 32-round bitwise
// threshold search (shfl-only, zero LDS, zero barriers, zero atomics), and
// writes enc>=T candidates to its PRIVATE 128-slot range + a count word.
// Superset proof: a global-top-64 member has <=63 greater globally, hence
// <=63 in its wave's subset, hence >= wave-T -> emitted.
__global__ void __launch_bounds__(64) k_top64_local(const float* __restrict__ mag,
                                                    u64* __restrict__ cand,
                                                    u32* __restrict__ wcnt) {
  const int blk = blockIdx.x;        // 448: 16 per bf
  const int bf = blk >> 4;
  const int wid = blk & 15;
  const int lane = threadIdx.x;
  const int wbase_elem = wid * 4096;
  const float4* m4 = (const float4*)(mag + (long long)bf * SEG + wbase_elem);

  u32 e[64];
#pragma unroll
  for (int k = 0; k < 16; ++k) {
    float4 v = m4[k * 64 + lane];
    e[4 * k + 0] = encf(v.x); e[4 * k + 1] = encf(v.y);
    e[4 * k + 2] = encf(v.z); e[4 * k + 3] = encf(v.w);
  }
  u32 T = 0u;
  for (int bit = 31; bit >= 0; --bit) {
    u32 Tt = T | (1u << bit);
    u32 c = 0;
#pragma unroll
    for (int k = 0; k < 64; ++k) c += (e[k] >= Tt) ? 1u : 0u;
#pragma unroll
    for (int off = 1; off < 64; off <<= 1) c += __shfl_xor(c, off, 64);
    if (c >= 64u) T = Tt;            // uniform across wave (full butterfly)
  }

  // ballot-compacted emission into private slots [bf*2048 + wid*128 ..]
  u64* dst = cand + (long long)bf * 2048 + wid * 128;
  u32 run = 0;
  const u64 below = (lane == 0) ? 0ull : (~0ull >> (64 - lane));
#pragma unroll
  for (int k = 0; k < 64; ++k) {
    bool cnd = (e[k] >= T);
    u64 mask = __ballot(cnd);
    if (cnd) {
      u32 off = run + (u32)__popcll(mask & below);
      if (off < 128u) {
        int s = wbase_elem + (k >> 2) * 256 + lane * 4 + (k & 3);
        dst[off] = ((u64)e[k] << 32) | (u64)(0xFFFFFFFFu - (u32)s);
      }
    }
    run += (u32)__popcll(mask);
  }
  if (lane == 0) wcnt[bf * 16 + wid] = (run < 128u) ? run : 128u;
}

// ---- fused merge + graph (28 blocks x 1024 — both phases are 28-shaped).
// Phase 2: compact per-wave candidate ranges into LDS, exact block-wide
// rank merge (keys unique) -> rank-ordered centers (FROZEN key order).
// Phases 3-4: FROZEN cov/inv/maha.
// Phase 5 (R13): radix-169 with 16-way lane-replicated bins + parallel
// suffix-inclusive scan. d* = max d with suffix_incl(d) >= need and
// need' = need - suffix_incl(d*+1): identical integers to the serial scan.
__global__ void __launch_bounds__(1024) k_merge_graph(const u64* __restrict__ cand,
                                                      const u32* __restrict__ wcnt,
                                                      float* __restrict__ out) {
  const int bf = blockIdx.x;
  const int tid = threadIdx.x;
  __shared__ u64 candk[2048];
  __shared__ u32 wbase[17];
  __shared__ float cy[64], cx[64];
  __shared__ float sinv[4];
  __shared__ u32 keys[4096];
  __shared__ u32 bins[256 * 16];     // bins[bin*16 + (tid&15)]
  __shared__ u32 stot[256];
  __shared__ u32 tie[4096];
  __shared__ u32 scal[4];

  if (tid == 0) {
    u32 acc = 0;
    for (int w = 0; w < 16; ++w) { wbase[w] = acc; acc += wcnt[bf * 16 + w]; }
    wbase[16] = acc;
  }
  __syncthreads();
  // compact candidates into LDS
  for (int w = 0; w < 16; ++w) {
    u32 cnt = wbase[w + 1] - wbase[w];
    for (u32 s = tid; s < cnt; s += 1024)
      candk[wbase[w] + s] = cand[(long long)bf * 2048 + w * 128 + s];
  }
  __syncthreads();
  u32 n = wbase[16];

  // exact rank merge -> rank-ordered centers
  for (u32 i = tid; i < n; i += 1024) {
    u64 mine = candk[i];
    int rank = 0;
    for (u32 j = 0; j < n; ++j) rank += (candk[j] > mine) ? 1 : 0;
    if (rank < 64) {
      int idx = (int)(0xFFFFFFFFu - (u32)(mine & 0xFFFFFFFFull));
      cy[rank] = (float)((idx >> 6) * 8 + 4);
      cx[rank] = (float)((idx & 63) * 8 + 4);
    }
  }
  __syncthreads();

  // mean/cov/inv — FROZEN sequential chains on thread 0
  if (tid == 0) {
    float sy = 0.f, sx = 0.f;
    for (int r = 0; r < 64; ++r) sy = __fadd_rn(sy, cy[r]);
    for (int r = 0; r < 64; ++r) sx = __fadd_rn(sx, cx[r]);
    float my = __fdiv_rn(sy, 64.0f), mx = __fdiv_rn(sx, 64.0f);
    float c00 = 0.f, c01 = 0.f, c11 = 0.f;
    for (int r = 0; r < 64; ++r) {
      float dy = __fsub_rn(cy[r], my);
      float dx = __fsub_rn(cx[r], mx);
      c00 = __fadd_rn(c00, __fmul_rn(dy, dy));
      c01 = __fadd_rn(c01, __fmul_rn(dy, dx));
      c11 = __fadd_rn(c11, __fmul_rn(dx, dx));
    }
    c00 = __fdiv_rn(c00, 63.0f); c01 = __fdiv_rn(c01, 63.0f); c11 = __fdiv_rn(c11, 63.0f);
    c00 = __fadd_rn(c00, 1e-6f); c11 = __fadd_rn(c11, 1e-6f);
    double det = (double)c00 * (double)c11 - (double)c01 * (double)c01;
    sinv[0] = (float)((double)c11 / det);
    sinv[1] = (float)(-(double)c01 / det);
    sinv[2] = sinv[1];
    sinv[3] = (float)((double)c00 / det);
  }
  __syncthreads();

  // maha keys + zero output — FROZEN arithmetic, order-independent
  float i00 = sinv[0], i01 = sinv[1], i10 = sinv[2], i11 = sinv[3];
  long long obase = (long long)bf * 4096;
  for (int ee = tid; ee < 4096; ee += 1024) {
    int q = ee >> 6, r = ee & 63;
    float d0 = __fsub_rn(cy[r], cy[q]);
    float d1 = __fsub_rn(cx[r], cx[q]);
    float v0 = __fadd_rn(__fadd_rn(0.0f, __fmul_rn(d0, i00)), __fmul_rn(d1, i10));
    float v1 = __fadd_rn(__fadd_rn(0.0f, __fmul_rn(d0, i01)), __fmul_rn(d1, i11));
    float p0 = __fmul_rn(v0, d0);
    float p1 = __fmul_rn(v1, d1);
    float s0 = __fsqrt_rn(p0);
    float s1 = __fsqrt_rn(p1);
    float mh = __fadd_rn(__fadd_rn(0.0f, s0), s1);
    u32 key;
    if (mh != mh) key = 0xFFFFFFFFu;   // NaN first (POLICY A, FROZEN)
    else key = encf(-mh);
    keys[ee] = key;
    out[obase + ee] = 0.0f;
  }
  __syncthreads();

  // phase 5 (R13): radix-select top-169, lane-replicated bins + par. scan
  u32 prefix = 0u, need = 169u;
  for (int pass = 0; pass < 4; ++pass) {
    int shift = 24 - pass * 8;
    if (tid == 0) scal[2] = 0u;
    for (int i = tid; i < 4096; i += 1024) bins[i] = 0u;
    __syncthreads();
    for (int k = 0; k < 4; ++k) {
      u32 ky = keys[tid + (k << 10)];
      bool ok = (pass == 0) || ((ky >> (shift + 8)) == (prefix >> (shift + 8)));
      if (ok) atomicAdd(&bins[(((ky >> shift) & 0xFFu) << 4) + (tid & 15)], 1u);
    }
    __syncthreads();
    if (tid < 256) {                       // per-bin totals (exact ints)
      u32 s = 0;
#pragma unroll
      for (int c = 0; c < 16; ++c) s += bins[(tid << 4) + c];
      stot[tid] = s;
    }
    __syncthreads();
    for (int off = 1; off < 256; off <<= 1) {   // suffix-inclusive scan
      u32 v = 0;
      if (tid < 256) {
        v = stot[tid];
        if (tid + off < 256) v += stot[tid + off];
      }
      __syncthreads();
      if (tid < 256) stot[tid] = v;
      __syncthreads();
    }
    if (tid < 256) {
      u32 si = stot[tid];
      u32 snext = (tid < 255) ? stot[tid + 1] : 0u;
      if (si >= need && snext < need) {    // unique by monotonicity
        scal[0] = prefix | ((u32)tid << shift);
        scal[1] = need - snext;
      }
    }
    __syncthreads();
    prefix = scal[0]; need = scal[1];
    __syncthreads();
  }
  for (int k = 0; k < 4; ++k) {
    int ee = tid + (k << 10);
    u32 ky = keys[ee];
    if (ky > prefix) out[obase + ee] = 1.0f;
    else if (ky == prefix) {
      u32 p = atomicAdd(&scal[2], 1u);
      tie[p] = (u32)ee;
    }
  }
  __syncthreads();
  int tc = (int)scal[2];
  for (int i = tid; i < tc; i += 1024) {
    u32 ei = tie[i];
    int rank = 0;
    for (int j = 0; j < tc; ++j) rank += (tie[j] < ei);
    if (rank < (int)need) out[obase + ei] = 1.0f;
  }
}

extern "C" void kernel_launch(void* const* d_in, const int* in_sizes, int n_in,
                              void* d_out, int out_size, void* d_ws, size_t ws_size,
                              hipStream_t stream) {
  if (ws_size < (size_t)WS_NEED) return;
  const float* x = (const float*)d_in[0];
  float* out = (float*)d_out;
  char* ws = (char*)d_ws;
  u32* mm = (u32*)(ws + WS_MM);
  float* corr = (float*)(ws + WS_CORR);
  u32* wcnt = (u32*)(ws + WS_WCNT);
  float* mag = (float*)(ws + WS_MAG);
  u32* mmpart = (u32*)(ws + WS_MMPART);   // overlaid on mag region
  u32* histc = (u32*)(ws + WS_HISTC);     // overlaid on mag region
  u64* cand = (u64*)d_out;                // consumed by k_merge_graph

  hipLaunchKernelGGL(k_minmax_pass, dim3(2048), dim3(256), 0, stream, x, mmpart);
  hipLaunchKernelGGL(k_mm_reduce, dim3(4), dim3(256), 0, stream, mmpart, mm);
  hipLaunchKernelGGL(k_hist_pass, dim3(2048), dim3(256), 0, stream, x, mm, histc);
  hipLaunchKernelGGL(k_corr, dim3(4), dim3(256), 0, stream, histc, corr);
  hipLaunchKernelGGL(k_mag_all, dim3(1024), dim3(256), 0, stream, x, corr, mag);
  hipLaunchKernelGGL(k_top64_local, dim3(448), dim3(64), 0, stream, mag, cand, wcnt);
  hipLaunchKernelGGL(k_merge_graph, dim3(28), dim3(1024), 0, stream, cand, wcnt, out);
}

// Round 14
// 205.166 us; speedup vs baseline: 1.2323x; 1.0317x over previous
//
#include <hip/hip_runtime.h>
#include <stdint.h>

// ============================================================================
// Motion_Relation_Mining — bit-exact replication of the JAX (CPU) reference.
//
// FROZEN (verified passing R0-R13, absmax 0.0): all f32 op sequences,
// NAN_POLICY_A, FMA-tanh, sequential reduce orders, selection key
// (enc(value)<<32)|~idx i.e. (value desc, index asc).
//
// R2: two-stage reductions replaced contended global atomics.
// R3: k_corr parallelized (scratch -> LDS, logs 100-wide).
// R4 (FAILED): ballot match-any — unroll spilled enc[] to scratch.
// R8: block-wide bitwise threshold search — barrier convoy (97us).
// R9: wave-autonomous threshold search (shfl-only, zero barriers).
// R10: k_mag_all (x read once), non-atomic hist partials, fused corr.
// R11 (FAILED): fusing top64 into the 28-block kernel throttled it.
// R12: 448x64 top64 + 28-block merge_graph.
// R13: radix-169 lane-replicated bins + parallel suffix scan (86->~25us).
// R14: k_hist_pass float4 loads + 32-way bins (4-way atomic serialization
//      1.58x -> 2-way free, m136) + rotated conflict-free flush reads.
//      k_mag_all re-tiled to 4 consecutive hw/thread: 32 float4 loads +
//      7 float4 stores (was 128 scalar loads + 28 scalar stores).
//      merge_graph bins widened to 32-way. All counts exact integers.
// ============================================================================

typedef unsigned int u32;
typedef unsigned long long u64;

// sizes
#define BB 4
#define TT 8
#define CC 16
#define HWN 65536              // H*W
#define NF 7
#define FRAME 1048576LL        // C*H*W
#define NELF 7340032.0f        // nf*C*H*W per batch (exact in f32)
#define NPAIR 28
#define SEG 65536

// ws layout (bytes)
#define WS_MM 0                // u32[24] final min/max (encoded)
#define WS_CORR 128            // float[4]
#define WS_WCNT 144            // u32[28][16] per-wave candidate counts
#define WS_MAG 16384           // float[28][65536]
// overlaid inside WS_MAG region — fully consumed before k_mag_all writes:
#define WS_MMPART (WS_MAG)            // u32[2048][6]  = 48 KiB
#define WS_HISTC  (WS_MAG + 65536)    // u32[2048][300] = 2.4 MiB
#define WS_NEED (16384 + 28LL*65536*4)
// candidate buffer lives in d_out: per bf a private 16KB range of
// 16 waves x 128 u64 slots. k_merge_graph consumes it (into LDS) before
// overwriting the same range with the output zeros/ones.

__device__ __forceinline__ u32 encf(float f) {
  u32 u = __float_as_uint(f);
  return (u & 0x80000000u) ? ~u : (u | 0x80000000u);
}
__device__ __forceinline__ float decf(u32 e) {
  u32 u = (e & 0x80000000u) ? (e ^ 0x80000000u) : ~e;
  return __uint_as_float(u);
}

// ---- single pass over frames: per-batch min/max of x_t, x_t1, x_t*x_t1.
// float4 loads; min/max order-free; product elementwise -> exact.
__global__ void k_minmax_pass(const float* __restrict__ x, u32* __restrict__ part) {
  const int blk = blockIdx.x;            // 2048 blocks: 512 per batch
  const int b = blk >> 9;
  const long long w0 = (long long)(blk & 511) * 2048;
  const int tid = threadIdx.x;
  u32 mn0 = 0xFFFFFFFFu, mx0 = 0u, mn1 = 0xFFFFFFFFu, mx1 = 0u,
      mnp = 0xFFFFFFFFu, mxp = 0u;
  float4 pv0, pv1;
  for (int t = 0; t < 8; ++t) {
    const float4* fp = (const float4*)(x + ((long long)(b * TT + t)) * FRAME + w0);
    float4 v0 = fp[tid];
    float4 v1 = fp[tid + 256];
#define MM_COMP(vc, pc)                                                     \
    {                                                                       \
      u32 ev = encf(vc);                                                    \
      if (t < 7) { mn0 = min(mn0, ev); mx0 = max(mx0, ev); }                \
      if (t > 0) {                                                          \
        mn1 = min(mn1, ev); mx1 = max(mx1, ev);                             \
        u32 ep = encf(__fmul_rn(pc, vc));                                   \
        mnp = min(mnp, ep); mxp = max(mxp, ep);                             \
      }                                                                     \
    }
    MM_COMP(v0.x, pv0.x) MM_COMP(v0.y, pv0.y) MM_COMP(v0.z, pv0.z) MM_COMP(v0.w, pv0.w)
    MM_COMP(v1.x, pv1.x) MM_COMP(v1.y, pv1.y) MM_COMP(v1.z, pv1.z) MM_COMP(v1.w, pv1.w)
#undef MM_COMP
    pv0 = v0; pv1 = v1;
  }
  __shared__ u32 sm[6][256];
  sm[0][tid] = mn0; sm[1][tid] = mx0; sm[2][tid] = mn1;
  sm[3][tid] = mx1; sm[4][tid] = mnp; sm[5][tid] = mxp;
  __syncthreads();
  for (int st = 128; st > 0; st >>= 1) {
    if (tid < st) {
      sm[0][tid] = min(sm[0][tid], sm[0][tid + st]);
      sm[1][tid] = max(sm[1][tid], sm[1][tid + st]);
      sm[2][tid] = min(sm[2][tid], sm[2][tid + st]);
      sm[3][tid] = max(sm[3][tid], sm[3][tid + st]);
      sm[4][tid] = min(sm[4][tid], sm[4][tid + st]);
      sm[5][tid] = max(sm[5][tid], sm[5][tid + st]);
    }
    __syncthreads();
  }
  if (tid == 0) {
    u32* o = part + blk * 6;
    o[0] = sm[0][0]; o[1] = sm[1][0]; o[2] = sm[2][0];
    o[3] = sm[3][0]; o[4] = sm[4][0]; o[5] = sm[5][0];
  }
}

// 4 blocks (one per batch): reduce 512 partials -> mm[b*6..]
__global__ void k_mm_reduce(const u32* __restrict__ part, u32* __restrict__ mm) {
  const int b = blockIdx.x;
  const int tid = threadIdx.x;
  const u32* p0 = part + (b * 512 + tid) * 6;
  const u32* p1 = p0 + 256 * 6;
  __shared__ u32 sm[6][256];
  sm[0][tid] = min(p0[0], p1[0]); sm[1][tid] = max(p0[1], p1[1]);
  sm[2][tid] = min(p0[2], p1[2]); sm[3][tid] = max(p0[3], p1[3]);
  sm[4][tid] = min(p0[4], p1[4]); sm[5][tid] = max(p0[5], p1[5]);
  __syncthreads();
  for (int st = 128; st > 0; st >>= 1) {
    if (tid < st) {
      sm[0][tid] = min(sm[0][tid], sm[0][tid + st]);
      sm[1][tid] = max(sm[1][tid], sm[1][tid + st]);
      sm[2][tid] = min(sm[2][tid], sm[2][tid + st]);
      sm[3][tid] = max(sm[3][tid], sm[3][tid + st]);
      sm[4][tid] = min(sm[4][tid], sm[4][tid + st]);
      sm[5][tid] = max(sm[5][tid], sm[5][tid + st]);
    }
    __syncthreads();
  }
  if (tid == 0)
    for (int i = 0; i < 6; ++i) mm[b * 6 + i] = sm[i][0];
}

__device__ __forceinline__ int bin_of(float v, float vmin, float den) {
  float tt = __fsub_rn(v, vmin);
  float q = __fdiv_rn(tt, den);
  float z = __fmul_rn(q, 100.0f);
  z = fminf(fmaxf(z, 0.0f), 99.0f);
  return (int)z;
}

// ---- single pass over frames (R14): float4 loads + 32-way lane-replicated
// LDS sub-histograms (2 lanes/sub -> 2-way same-address = free, m136),
// flushed NON-atomically (rotated conflict-free reads) to this block's
// private 300-u32 partial.
__global__ void k_hist_pass(const float* __restrict__ x, const u32* __restrict__ mm,
                            u32* __restrict__ histc) {
  __shared__ u32 h[300 * 32];            // h[bin*32 + (tid&31)]
  for (int i = threadIdx.x; i < 9600; i += 256) h[i] = 0u;
  __syncthreads();
  const int blk = blockIdx.x;
  const int b = blk >> 9;
  const long long w0 = (long long)(blk & 511) * 2048;
  const int tid = threadIdx.x;
  const int sub = tid & 31;
  float mn_t = decf(mm[6 * b + 0]), den_t = __fsub_rn(decf(mm[6 * b + 1]), decf(mm[6 * b + 0]));
  float mn_1 = decf(mm[6 * b + 2]), den_1 = __fsub_rn(decf(mm[6 * b + 3]), decf(mm[6 * b + 2]));
  float mn_p = decf(mm[6 * b + 4]), den_p = __fsub_rn(decf(mm[6 * b + 5]), decf(mm[6 * b + 4]));
  float4 pv0, pv1;
  for (int t = 0; t < 8; ++t) {
    const float4* fp = (const float4*)(x + ((long long)(b * TT + t)) * FRAME + w0);
    float4 v0 = fp[tid];
    float4 v1 = fp[tid + 256];
#define HH_COMP(vc, pc)                                                       \
    {                                                                         \
      if (t < 7) atomicAdd(&h[bin_of(vc, mn_t, den_t) * 32 + sub], 1u);       \
      if (t > 0) {                                                            \
        atomicAdd(&h[(100 + bin_of(vc, mn_1, den_1)) * 32 + sub], 1u);        \
        float p = __fmul_rn(pc, vc);                                          \
        atomicAdd(&h[(200 + bin_of(p, mn_p, den_p)) * 32 + sub], 1u);         \
      }                                                                       \
    }
    HH_COMP(v0.x, pv0.x) HH_COMP(v0.y, pv0.y) HH_COMP(v0.z, pv0.z) HH_COMP(v0.w, pv0.w)
    HH_COMP(v1.x, pv1.x) HH_COMP(v1.y, pv1.y) HH_COMP(v1.z, pv1.z) HH_COMP(v1.w, pv1.w)
#undef HH_COMP
    pv0 = v0; pv1 = v1;
  }
  __syncthreads();
  u32* dst = histc + blk * 300;
  for (int i = threadIdx.x; i < 300; i += 256) {
    u32 s = 0;
#pragma unroll
    for (int c = 0; c < 32; ++c)
      s += h[i * 32 + ((c + i) & 31)];   // rotated: conflict-free banks
    dst[i] = s;                          // non-atomic private partial
  }
}

// Eigen/XLA fast-tanh rational interpolant (FMA form) — FROZEN
__device__ float tanh_emul(float a) {
  const float kClamp = 7.90531110763549805f;
  float xx = fminf(fmaxf(a, -kClamp), kClamp);
  float x2 = __fmul_rn(xx, xx);
  float p = __fmaf_rn(x2, -2.76076847742355e-16f, 2.00018790482477e-13f);
  p = __fmaf_rn(x2, p, -8.60467152213735e-11f);
  p = __fmaf_rn(x2, p, 5.12229709037114e-08f);
  p = __fmaf_rn(x2, p, 1.48572235717979e-05f);
  p = __fmaf_rn(x2, p, 6.37261928875436e-04f);
  p = __fmaf_rn(x2, p, 4.89352455891786e-03f);
  p = __fmul_rn(xx, p);
  float q = __fmaf_rn(x2, 1.19825839466702e-06f, 1.18534705686654e-04f);
  q = __fmaf_rn(x2, q, 2.26843463243900e-03f);
  q = __fmaf_rn(x2, q, 4.89352518554385e-03f);
  float r = __fdiv_rn(p, q);
  if (fabsf(a) < 0.0004f) r = a;
  return r;
}

// ---- per-batch: sum 512 partial histograms (8-way ILP, exact ints),
// then mi/corr with FROZEN sequential chains on thread 0.
__global__ void __launch_bounds__(256) k_corr(const u32* __restrict__ histc,
                                              float* __restrict__ corr) {
  const int b = blockIdx.x;
  const int tid = threadIdx.x;
  __shared__ u32 shist[300];
  __shared__ float shx[100], shx1[100], sterm[100];
  __shared__ float ssum[3];
  for (int i = tid; i < 300; i += 256) {
    const u32* src = histc + (long long)(b * 512) * 300 + i;
    u32 s0 = 0, s1 = 0, s2 = 0, s3 = 0, s4 = 0, s5 = 0, s6 = 0, s7 = 0;
    for (int c = 0; c < 512; c += 8) {   // 8 independent load chains (ILP)
      s0 += src[(c + 0) * 300]; s1 += src[(c + 1) * 300];
      s2 += src[(c + 2) * 300]; s3 += src[(c + 3) * 300];
      s4 += src[(c + 4) * 300]; s5 += src[(c + 5) * 300];
      s6 += src[(c + 6) * 300]; s7 += src[(c + 7) * 300];
    }
    shist[i] = ((s0 + s1) + (s2 + s3)) + ((s4 + s5) + (s6 + s7));
  }
  __syncthreads();
  const u32* HX = shist;
  const u32* HX1 = shist + 100;
  const u32* HJ = shist + 200;
  if (tid < 100) {
    shx[tid] = __fdiv_rn((float)HX[tid], NELF);
    shx1[tid] = __fdiv_rn((float)HX1[tid], NELF);
  }
  __syncthreads();
  if (tid == 0) {
    float Sj = 0.0f;
    for (int i = 0; i < 100; ++i) Sj = __fadd_rn(Sj, (float)HJ[i]);
    float Sx = 0.0f, Sx1 = 0.0f;
    for (int i = 0; i < 100; ++i) Sx = __fadd_rn(Sx, shx[i]);
    for (int i = 0; i < 100; ++i) Sx1 = __fadd_rn(Sx1, shx1[i]);
    ssum[0] = Sj; ssum[1] = Sx; ssum[2] = Sx1;
  }
  __syncthreads();
  if (tid < 100) {
    float Sj = ssum[0], Sx = ssum[1], Sx1 = ssum[2];
    float pj = __fdiv_rn((float)HJ[tid], Sj);
    float px = __fdiv_rn(shx[tid], Sx);
    float px1 = __fdiv_rn(shx1[tid], Sx1);
    float la = (float)log((double)__fadd_rn(pj, 1e-10f));
    float lb = (float)log((double)__fadd_rn(__fmul_rn(px, px1), 1e-10f));
    sterm[tid] = __fmul_rn(pj, __fsub_rn(la, lb));
  }
  __syncthreads();
  if (tid == 0) {
    float mi = 0.0f;
    for (int i = 0; i < 100; ++i) mi = __fadd_rn(mi, sterm[i]);
    float lm = (float)log((double)mi);
    float th = tanh_emul(lm);
    float num = (float)exp(0.8);
    corr[b] = __fdiv_rn(num, th);
  }
}

// ---- mag for ALL 7 pairs, 4 consecutive hw per thread (R14): 32 float4
// loads + 7 float4 stores (col-aligned-4 keeps s-swizzle runs contiguous).
// Each pixel's per-c chain keeps the FROZEN sequential order.
__global__ void k_mag_all(const float* __restrict__ x, const float* __restrict__ corr,
                          float* __restrict__ mag) {
  int gid = blockIdx.x * 256 + threadIdx.x;   // 0..65535 = (b, hw/4)
  int b = gid >> 14;
  int hw0 = (gid & 16383) << 2;
  int row = hw0 >> 8, col = hw0 & 255;
  int g = (row >> 3) * 32 + (col >> 3);
  int s0 = g * 64 + (row & 7) * 8 + (col & 7);  // divisible by 4
  const float cb = corr[b];
  const float4* xp = (const float4*)(x + (long long)b * TT * FRAME + hw0);
  float4 acc[7];
#pragma unroll
  for (int f = 0; f < 7; ++f) acc[f] = make_float4(0.f, 0.f, 0.f, 0.f);
  for (int c = 0; c < CC; ++c) {
    float4 v[8];
#pragma unroll
    for (int t = 0; t < 8; ++t)
      v[t] = xp[(t * CC + c) << 14];            // (t*16+c)*65536/4
#pragma unroll
    for (int f = 0; f < 7; ++f) {
      acc[f].x = __fadd_rn(acc[f].x, __fadd_rn(__fsub_rn(v[f + 1].x, v[f].x), cb));
      acc[f].y = __fadd_rn(acc[f].y, __fadd_rn(__fsub_rn(v[f + 1].y, v[f].y), cb));
      acc[f].z = __fadd_rn(acc[f].z, __fadd_rn(__fsub_rn(v[f + 1].z, v[f].z), cb));
      acc[f].w = __fadd_rn(acc[f].w, __fadd_rn(__fsub_rn(v[f + 1].w, v[f].w), cb));
    }
  }
  float4* mp = (float4*)(mag + (((long long)(b * NF)) << 16));
#pragma unroll
  for (int f = 0; f < 7; ++f)
    mp[(f << 14) + (s0 >> 2)] = acc[f];
}

// ---- top-64 stage 1: 448 blocks x ONE WAVE. Each wave owns 4096 mag
// elements in registers, finds its own 64th-largest via 32-round bitwise
// threshold search (shfl-only, zero LDS, zero barriers, zero atomics), and
// writes enc>=T candidates to its PRIVATE 128-slot range + a count word.
// Superset proof: a global-top-64 member has <=63 greater globally, hence
// <=63 in its wave's subset, hence >= wave-T -> emitted.
__global__ void __launch_bounds__(64) k_top64_local(const float* __restrict__ mag,
                                                    u64* __restrict__ cand,
                                                    u32* __restrict__ wcnt) {
  const int blk = blockIdx.x;        // 448: 16 per bf
  const int bf = blk >> 4;
  const int wid = blk & 15;
  const int lane = threadIdx.x;
  const int wbase_elem = wid * 4096;
  const float4* m4 = (const float4*)(mag + (long long)bf * SEG + wbase_elem);

  u32 e[64];
#pragma unroll
  for (int k = 0; k < 16; ++k) {
    float4 v = m4[k * 64 + lane];
    e[4 * k + 0] = encf(v.x); e[4 * k + 1] = encf(v.y);
    e[4 * k + 2] = encf(v.z); e[4 * k + 3] = encf(v.w);
  }
  u32 T = 0u;
  for (int bit = 31; bit >= 0; --bit) {
    u32 Tt = T | (1u << bit);
    u32 c = 0;
#pragma unroll
    for (int k = 0; k < 64; ++k) c += (e[k] >= Tt) ? 1u : 0u;
#pragma unroll
    for (int off = 1; off < 64; off <<= 1) c += __shfl_xor(c, off, 64);
    if (c >= 64u) T = Tt;            // uniform across wave (full butterfly)
  }

  // ballot-compacted emission into private slots [bf*2048 + wid*128 ..]
  u64* dst = cand + (long long)bf * 2048 + wid * 128;
  u32 run = 0;
  const u64 below = (lane == 0) ? 0ull : (~0ull >> (64 - lane));
#pragma unroll
  for (int k = 0; k < 64; ++k) {
    bool cnd = (e[k] >= T);
    u64 mask = __ballot(cnd);
    if (cnd) {
      u32 off = run + (u32)__popcll(mask & below);
      if (off < 128u) {
        int s = wbase_elem + (k >> 2) * 256 + lane * 4 + (k & 3);
        dst[off] = ((u64)e[k] << 32) | (u64)(0xFFFFFFFFu - (u32)s);
      }
    }
    run += (u32)__popcll(mask);
  }
  if (lane == 0) wcnt[bf * 16 + wid] = (run < 128u) ? run : 128u;
}

// ---- fused merge + graph (28 blocks x 1024 — both phases are 28-shaped).
// Phase 2: compact per-wave candidate ranges into LDS, exact block-wide
// rank merge (keys unique) -> rank-ordered centers (FROZEN key order).
// Phases 3-4: FROZEN cov/inv/maha.
// Phase 5: radix-169 with 32-way lane-replicated bins (R14) + parallel
// suffix-inclusive scan. Identical integers to the serial scan.
__global__ void __launch_bounds__(1024) k_merge_graph(const u64* __restrict__ cand,
                                                      const u32* __restrict__ wcnt,
                                                      float* __restrict__ out) {
  const int bf = blockIdx.x;
  const int tid = threadIdx.x;
  __shared__ u64 candk[2048];
  __shared__ u32 wbase[17];
  __shared__ float cy[64], cx[64];
  __shared__ float sinv[4];
  __shared__ u32 keys[4096];
  __shared__ u32 bins[256 * 32];     // bins[bin*32 + (tid&31)]
  __shared__ u32 stot[256];
  __shared__ u32 tie[4096];
  __shared__ u32 scal[4];

  if (tid == 0) {
    u32 acc = 0;
    for (int w = 0; w < 16; ++w) { wbase[w] = acc; acc += wcnt[bf * 16 + w]; }
    wbase[16] = acc;
  }
  __syncthreads();
  // compact candidates into LDS
  for (int w = 0; w < 16; ++w) {
    u32 cnt = wbase[w + 1] - wbase[w];
    for (u32 s = tid; s < cnt; s += 1024)
      candk[wbase[w] + s] = cand[(long long)bf * 2048 + w * 128 + s];
  }
  __syncthreads();
  u32 n = wbase[16];

  // exact rank merge -> rank-ordered centers
  for (u32 i = tid; i < n; i += 1024) {
    u64 mine = candk[i];
    int rank = 0;
    for (u32 j = 0; j < n; ++j) rank += (candk[j] > mine) ? 1 : 0;
    if (rank < 64) {
      int idx = (int)(0xFFFFFFFFu - (u32)(mine & 0xFFFFFFFFull));
      cy[rank] = (float)((idx >> 6) * 8 + 4);
      cx[rank] = (float)((idx & 63) * 8 + 4);
    }
  }
  __syncthreads();

  // mean/cov/inv — FROZEN sequential chains on thread 0
  if (tid == 0) {
    float sy = 0.f, sx = 0.f;
    for (int r = 0; r < 64; ++r) sy = __fadd_rn(sy, cy[r]);
    for (int r = 0; r < 64; ++r) sx = __fadd_rn(sx, cx[r]);
    float my = __fdiv_rn(sy, 64.0f), mx = __fdiv_rn(sx, 64.0f);
    float c00 = 0.f, c01 = 0.f, c11 = 0.f;
    for (int r = 0; r < 64; ++r) {
      float dy = __fsub_rn(cy[r], my);
      float dx = __fsub_rn(cx[r], mx);
      c00 = __fadd_rn(c00, __fmul_rn(dy, dy));
      c01 = __fadd_rn(c01, __fmul_rn(dy, dx));
      c11 = __fadd_rn(c11, __fmul_rn(dx, dx));
    }
    c00 = __fdiv_rn(c00, 63.0f); c01 = __fdiv_rn(c01, 63.0f); c11 = __fdiv_rn(c11, 63.0f);
    c00 = __fadd_rn(c00, 1e-6f); c11 = __fadd_rn(c11, 1e-6f);
    double det = (double)c00 * (double)c11 - (double)c01 * (double)c01;
    sinv[0] = (float)((double)c11 / det);
    sinv[1] = (float)(-(double)c01 / det);
    sinv[2] = sinv[1];
    sinv[3] = (float)((double)c00 / det);
  }
  __syncthreads();

  // maha keys + zero output — FROZEN arithmetic, order-independent
  float i00 = sinv[0], i01 = sinv[1], i10 = sinv[2], i11 = sinv[3];
  long long obase = (long long)bf * 4096;
  for (int ee = tid; ee < 4096; ee += 1024) {
    int q = ee >> 6, r = ee & 63;
    float d0 = __fsub_rn(cy[r], cy[q]);
    float d1 = __fsub_rn(cx[r], cx[q]);
    float v0 = __fadd_rn(__fadd_rn(0.0f, __fmul_rn(d0, i00)), __fmul_rn(d1, i10));
    float v1 = __fadd_rn(__fadd_rn(0.0f, __fmul_rn(d0, i01)), __fmul_rn(d1, i11));
    float p0 = __fmul_rn(v0, d0);
    float p1 = __fmul_rn(v1, d1);
    float s0 = __fsqrt_rn(p0);
    float s1 = __fsqrt_rn(p1);
    float mh = __fadd_rn(__fadd_rn(0.0f, s0), s1);
    u32 key;
    if (mh != mh) key = 0xFFFFFFFFu;   // NaN first (POLICY A, FROZEN)
    else key = encf(-mh);
    keys[ee] = key;
    out[obase + ee] = 0.0f;
  }
  __syncthreads();

  // phase 5: radix-select top-169, 32-way replicated bins + parallel scan
  u32 prefix = 0u, need = 169u;
  for (int pass = 0; pass < 4; ++pass) {
    int shift = 24 - pass * 8;
    if (tid == 0) scal[2] = 0u;
    for (int i = tid; i < 8192; i += 1024) bins[i] = 0u;
    __syncthreads();
    for (int k = 0; k < 4; ++k) {
      u32 ky = keys[tid + (k << 10)];
      bool ok = (pass == 0) || ((ky >> (shift + 8)) == (prefix >> (shift + 8)));
      if (ok) atomicAdd(&bins[(((ky >> shift) & 0xFFu) << 5) + (tid & 31)], 1u);
    }
    __syncthreads();
    if (tid < 256) {                       // per-bin totals (rotated reads)
      u32 s = 0;
#pragma unroll
      for (int c = 0; c < 32; ++c) s += bins[(tid << 5) + ((c + tid) & 31)];
      stot[tid] = s;
    }
    __syncthreads();
    for (int off = 1; off < 256; off <<= 1) {   // suffix-inclusive scan
      u32 v = 0;
      if (tid < 256) {
        v = stot[tid];
        if (tid + off < 256) v += stot[tid + off];
      }
      __syncthreads();
      if (tid < 256) stot[tid] = v;
      __syncthreads();
    }
    if (tid < 256) {
      u32 si = stot[tid];
      u32 snext = (tid < 255) ? stot[tid + 1] : 0u;
      if (si >= need && snext < need) {    // unique by monotonicity
        scal[0] = prefix | ((u32)tid << shift);
        scal[1] = need - snext;
      }
    }
    __syncthreads();
    prefix = scal[0]; need = scal[1];
    __syncthreads();
  }
  for (int k = 0; k < 4; ++k) {
    int ee = tid + (k << 10);
    u32 ky = keys[ee];
    if (ky > prefix) out[obase + ee] = 1.0f;
    else if (ky == prefix) {
      u32 p = atomicAdd(&scal[2], 1u);
      tie[p] = (u32)ee;
    }
  }
  __syncthreads();
  int tc = (int)scal[2];
  for (int i = tid; i < tc; i += 1024) {
    u32 ei = tie[i];
    int rank = 0;
    for (int j = 0; j < tc; ++j) rank += (tie[j] < ei);
    if (rank < (int)need) out[obase + ei] = 1.0f;
  }
}

extern "C" void kernel_launch(void* const* d_in, const int* in_sizes, int n_in,
                              void* d_out, int out_size, void* d_ws, size_t ws_size,
                              hipStream_t stream) {
  if (ws_size < (size_t)WS_NEED) return;
  const float* x = (const float*)d_in[0];
  float* out = (float*)d_out;
  char* ws = (char*)d_ws;
  u32* mm = (u32*)(ws + WS_MM);
  float* corr = (float*)(ws + WS_CORR);
  u32* wcnt = (u32*)(ws + WS_WCNT);
  float* mag = (float*)(ws + WS_MAG);
  u32* mmpart = (u32*)(ws + WS_MMPART);   // overlaid on mag region
  u32* histc = (u32*)(ws + WS_HISTC);     // overlaid on mag region
  u64* cand = (u64*)d_out;                // consumed by k_merge_graph

  hipLaunchKernelGGL(k_minmax_pass, dim3(2048), dim3(256), 0, stream, x, mmpart);
  hipLaunchKernelGGL(k_mm_reduce, dim3(4), dim3(256), 0, stream, mmpart, mm);
  hipLaunchKernelGGL(k_hist_pass, dim3(2048), dim3(256), 0, stream, x, mm, histc);
  hipLaunchKernelGGL(k_corr, dim3(4), dim3(256), 0, stream, histc, corr);
  hipLaunchKernelGGL(k_mag_all, dim3(256), dim3(256), 0, stream, x, corr, mag);
  hipLaunchKernelGGL(k_top64_local, dim3(448), dim3(64), 0, stream, mag, cand, wcnt);
  hipLaunchKernelGGL(k_merge_graph, dim3(28), dim3(1024), 0, stream, cand, wcnt, out);
}

// Round 15
// 200.181 us; speedup vs baseline: 1.2630x; 1.0249x over previous
//
#include <hip/hip_runtime.h>
#include <stdint.h>

// ============================================================================
// Motion_Relation_Mining — bit-exact replication of the JAX (CPU) reference.
//
// FROZEN (verified passing R0-R14, absmax 0.0): all f32 op sequences,
// NAN_POLICY_A, FMA-tanh, sequential reduce orders, selection key
// (enc(value)<<32)|~idx i.e. (value desc, index asc).
//
// R2: two-stage reductions replaced contended global atomics.
// R3: k_corr parallelized (scratch -> LDS, logs 100-wide).
// R4 (FAILED): ballot match-any — unroll spilled enc[] to scratch.
// R8: block-wide bitwise threshold search — barrier convoy (97us).
// R9: wave-autonomous threshold search (shfl-only, zero barriers).
// R10: k_mag_all (x read once), non-atomic hist partials, fused corr.
// R11 (FAILED): fusing top64 into the 28-block kernel throttled it.
// R12: 448x64 top64 + 28-block merge_graph.
// R13/R14: radix-169 32-way replicated bins + parallel scan (conflicts
//      1.78M -> 52) — but merge_graph STILL 75us at VALUBusy 2.5%.
// R15: the real cost was dependent-latency LDS chains: the rank-merge
//      inner loop has a RUNTIME bound -> compiler can't unroll -> 1100
//      single-outstanding ds_read_b64 @ ~120cy = ~55us. Fixes: 8-way
//      manual unroll (8 loads in flight), wave-parallel wbase scan,
//      per-wave compaction, wave-0 shfl suffix scan (64 barriers dropped).
//      All integer/order-free -> bit-exact.
// ============================================================================

typedef unsigned int u32;
typedef unsigned long long u64;

// sizes
#define BB 4
#define TT 8
#define CC 16
#define HWN 65536              // H*W
#define NF 7
#define FRAME 1048576LL        // C*H*W
#define NELF 7340032.0f        // nf*C*H*W per batch (exact in f32)
#define NPAIR 28
#define SEG 65536

// ws layout (bytes)
#define WS_MM 0                // u32[24] final min/max (encoded)
#define WS_CORR 128            // float[4]
#define WS_WCNT 144            // u32[28][16] per-wave candidate counts
#define WS_MAG 16384           // float[28][65536]
// overlaid inside WS_MAG region — fully consumed before k_mag_all writes:
#define WS_MMPART (WS_MAG)            // u32[2048][6]  = 48 KiB
#define WS_HISTC  (WS_MAG + 65536)    // u32[2048][300] = 2.4 MiB
#define WS_NEED (16384 + 28LL*65536*4)
// candidate buffer lives in d_out: per bf a private 16KB range of
// 16 waves x 128 u64 slots. k_merge_graph consumes it (into LDS) before
// overwriting the same range with the output zeros/ones.

__device__ __forceinline__ u32 encf(float f) {
  u32 u = __float_as_uint(f);
  return (u & 0x80000000u) ? ~u : (u | 0x80000000u);
}
__device__ __forceinline__ float decf(u32 e) {
  u32 u = (e & 0x80000000u) ? (e ^ 0x80000000u) : ~e;
  return __uint_as_float(u);
}

// ---- single pass over frames: per-batch min/max of x_t, x_t1, x_t*x_t1.
// float4 loads; min/max order-free; product elementwise -> exact.
__global__ void k_minmax_pass(const float* __restrict__ x, u32* __restrict__ part) {
  const int blk = blockIdx.x;            // 2048 blocks: 512 per batch
  const int b = blk >> 9;
  const long long w0 = (long long)(blk & 511) * 2048;
  const int tid = threadIdx.x;
  u32 mn0 = 0xFFFFFFFFu, mx0 = 0u, mn1 = 0xFFFFFFFFu, mx1 = 0u,
      mnp = 0xFFFFFFFFu, mxp = 0u;
  float4 pv0, pv1;
  for (int t = 0; t < 8; ++t) {
    const float4* fp = (const float4*)(x + ((long long)(b * TT + t)) * FRAME + w0);
    float4 v0 = fp[tid];
    float4 v1 = fp[tid + 256];
#define MM_COMP(vc, pc)                                                     \
    {                                                                       \
      u32 ev = encf(vc);                                                    \
      if (t < 7) { mn0 = min(mn0, ev); mx0 = max(mx0, ev); }                \
      if (t > 0) {                                                          \
        mn1 = min(mn1, ev); mx1 = max(mx1, ev);                             \
        u32 ep = encf(__fmul_rn(pc, vc));                                   \
        mnp = min(mnp, ep); mxp = max(mxp, ep);                             \
      }                                                                     \
    }
    MM_COMP(v0.x, pv0.x) MM_COMP(v0.y, pv0.y) MM_COMP(v0.z, pv0.z) MM_COMP(v0.w, pv0.w)
    MM_COMP(v1.x, pv1.x) MM_COMP(v1.y, pv1.y) MM_COMP(v1.z, pv1.z) MM_COMP(v1.w, pv1.w)
#undef MM_COMP
    pv0 = v0; pv1 = v1;
  }
  __shared__ u32 sm[6][256];
  sm[0][tid] = mn0; sm[1][tid] = mx0; sm[2][tid] = mn1;
  sm[3][tid] = mx1; sm[4][tid] = mnp; sm[5][tid] = mxp;
  __syncthreads();
  for (int st = 128; st > 0; st >>= 1) {
    if (tid < st) {
      sm[0][tid] = min(sm[0][tid], sm[0][tid + st]);
      sm[1][tid] = max(sm[1][tid], sm[1][tid + st]);
      sm[2][tid] = min(sm[2][tid], sm[2][tid + st]);
      sm[3][tid] = max(sm[3][tid], sm[3][tid + st]);
      sm[4][tid] = min(sm[4][tid], sm[4][tid + st]);
      sm[5][tid] = max(sm[5][tid], sm[5][tid + st]);
    }
    __syncthreads();
  }
  if (tid == 0) {
    u32* o = part + blk * 6;
    o[0] = sm[0][0]; o[1] = sm[1][0]; o[2] = sm[2][0];
    o[3] = sm[3][0]; o[4] = sm[4][0]; o[5] = sm[5][0];
  }
}

// 4 blocks (one per batch): reduce 512 partials -> mm[b*6..]
__global__ void k_mm_reduce(const u32* __restrict__ part, u32* __restrict__ mm) {
  const int b = blockIdx.x;
  const int tid = threadIdx.x;
  const u32* p0 = part + (b * 512 + tid) * 6;
  const u32* p1 = p0 + 256 * 6;
  __shared__ u32 sm[6][256];
  sm[0][tid] = min(p0[0], p1[0]); sm[1][tid] = max(p0[1], p1[1]);
  sm[2][tid] = min(p0[2], p1[2]); sm[3][tid] = max(p0[3], p1[3]);
  sm[4][tid] = min(p0[4], p1[4]); sm[5][tid] = max(p0[5], p1[5]);
  __syncthreads();
  for (int st = 128; st > 0; st >>= 1) {
    if (tid < st) {
      sm[0][tid] = min(sm[0][tid], sm[0][tid + st]);
      sm[1][tid] = max(sm[1][tid], sm[1][tid + st]);
      sm[2][tid] = min(sm[2][tid], sm[2][tid + st]);
      sm[3][tid] = max(sm[3][tid], sm[3][tid + st]);
      sm[4][tid] = min(sm[4][tid], sm[4][tid + st]);
      sm[5][tid] = max(sm[5][tid], sm[5][tid + st]);
    }
    __syncthreads();
  }
  if (tid == 0)
    for (int i = 0; i < 6; ++i) mm[b * 6 + i] = sm[i][0];
}

__device__ __forceinline__ int bin_of(float v, float vmin, float den) {
  float tt = __fsub_rn(v, vmin);
  float q = __fdiv_rn(tt, den);
  float z = __fmul_rn(q, 100.0f);
  z = fminf(fmaxf(z, 0.0f), 99.0f);
  return (int)z;
}

// ---- single pass over frames: float4 loads + 32-way lane-replicated
// LDS sub-histograms (2-way same-address = free, m136), flushed
// NON-atomically (rotated conflict-free reads) to the block's partial.
__global__ void k_hist_pass(const float* __restrict__ x, const u32* __restrict__ mm,
                            u32* __restrict__ histc) {
  __shared__ u32 h[300 * 32];            // h[bin*32 + (tid&31)]
  for (int i = threadIdx.x; i < 9600; i += 256) h[i] = 0u;
  __syncthreads();
  const int blk = blockIdx.x;
  const int b = blk >> 9;
  const long long w0 = (long long)(blk & 511) * 2048;
  const int tid = threadIdx.x;
  const int sub = tid & 31;
  float mn_t = decf(mm[6 * b + 0]), den_t = __fsub_rn(decf(mm[6 * b + 1]), decf(mm[6 * b + 0]));
  float mn_1 = decf(mm[6 * b + 2]), den_1 = __fsub_rn(decf(mm[6 * b + 3]), decf(mm[6 * b + 2]));
  float mn_p = decf(mm[6 * b + 4]), den_p = __fsub_rn(decf(mm[6 * b + 5]), decf(mm[6 * b + 4]));
  float4 pv0, pv1;
  for (int t = 0; t < 8; ++t) {
    const float4* fp = (const float4*)(x + ((long long)(b * TT + t)) * FRAME + w0);
    float4 v0 = fp[tid];
    float4 v1 = fp[tid + 256];
#define HH_COMP(vc, pc)                                                       \
    {                                                                         \
      if (t < 7) atomicAdd(&h[bin_of(vc, mn_t, den_t) * 32 + sub], 1u);       \
      if (t > 0) {                                                            \
        atomicAdd(&h[(100 + bin_of(vc, mn_1, den_1)) * 32 + sub], 1u);        \
        float p = __fmul_rn(pc, vc);                                          \
        atomicAdd(&h[(200 + bin_of(p, mn_p, den_p)) * 32 + sub], 1u);         \
      }                                                                       \
    }
    HH_COMP(v0.x, pv0.x) HH_COMP(v0.y, pv0.y) HH_COMP(v0.z, pv0.z) HH_COMP(v0.w, pv0.w)
    HH_COMP(v1.x, pv1.x) HH_COMP(v1.y, pv1.y) HH_COMP(v1.z, pv1.z) HH_COMP(v1.w, pv1.w)
#undef HH_COMP
    pv0 = v0; pv1 = v1;
  }
  __syncthreads();
  u32* dst = histc + blk * 300;
  for (int i = threadIdx.x; i < 300; i += 256) {
    u32 s = 0;
#pragma unroll
    for (int c = 0; c < 32; ++c)
      s += h[i * 32 + ((c + i) & 31)];   // rotated: conflict-free banks
    dst[i] = s;                          // non-atomic private partial
  }
}

// Eigen/XLA fast-tanh rational interpolant (FMA form) — FROZEN
__device__ float tanh_emul(float a) {
  const float kClamp = 7.90531110763549805f;
  float xx = fminf(fmaxf(a, -kClamp), kClamp);
  float x2 = __fmul_rn(xx, xx);
  float p = __fmaf_rn(x2, -2.76076847742355e-16f, 2.00018790482477e-13f);
  p = __fmaf_rn(x2, p, -8.60467152213735e-11f);
  p = __fmaf_rn(x2, p, 5.12229709037114e-08f);
  p = __fmaf_rn(x2, p, 1.48572235717979e-05f);
  p = __fmaf_rn(x2, p, 6.37261928875436e-04f);
  p = __fmaf_rn(x2, p, 4.89352455891786e-03f);
  p = __fmul_rn(xx, p);
  float q = __fmaf_rn(x2, 1.19825839466702e-06f, 1.18534705686654e-04f);
  q = __fmaf_rn(x2, q, 2.26843463243900e-03f);
  q = __fmaf_rn(x2, q, 4.89352518554385e-03f);
  float r = __fdiv_rn(p, q);
  if (fabsf(a) < 0.0004f) r = a;
  return r;
}

// ---- per-batch: sum 512 partial histograms (8-way ILP, exact ints),
// then mi/corr with FROZEN sequential chains on thread 0.
__global__ void __launch_bounds__(256) k_corr(const u32* __restrict__ histc,
                                              float* __restrict__ corr) {
  const int b = blockIdx.x;
  const int tid = threadIdx.x;
  __shared__ u32 shist[300];
  __shared__ float shx[100], shx1[100], sterm[100];
  __shared__ float ssum[3];
  for (int i = tid; i < 300; i += 256) {
    const u32* src = histc + (long long)(b * 512) * 300 + i;
    u32 s0 = 0, s1 = 0, s2 = 0, s3 = 0, s4 = 0, s5 = 0, s6 = 0, s7 = 0;
    for (int c = 0; c < 512; c += 8) {   // 8 independent load chains (ILP)
      s0 += src[(c + 0) * 300]; s1 += src[(c + 1) * 300];
      s2 += src[(c + 2) * 300]; s3 += src[(c + 3) * 300];
      s4 += src[(c + 4) * 300]; s5 += src[(c + 5) * 300];
      s6 += src[(c + 6) * 300]; s7 += src[(c + 7) * 300];
    }
    shist[i] = ((s0 + s1) + (s2 + s3)) + ((s4 + s5) + (s6 + s7));
  }
  __syncthreads();
  const u32* HX = shist;
  const u32* HX1 = shist + 100;
  const u32* HJ = shist + 200;
  if (tid < 100) {
    shx[tid] = __fdiv_rn((float)HX[tid], NELF);
    shx1[tid] = __fdiv_rn((float)HX1[tid], NELF);
  }
  __syncthreads();
  if (tid == 0) {
    float Sj = 0.0f;
    for (int i = 0; i < 100; ++i) Sj = __fadd_rn(Sj, (float)HJ[i]);
    float Sx = 0.0f, Sx1 = 0.0f;
    for (int i = 0; i < 100; ++i) Sx = __fadd_rn(Sx, shx[i]);
    for (int i = 0; i < 100; ++i) Sx1 = __fadd_rn(Sx1, shx1[i]);
    ssum[0] = Sj; ssum[1] = Sx; ssum[2] = Sx1;
  }
  __syncthreads();
  if (tid < 100) {
    float Sj = ssum[0], Sx = ssum[1], Sx1 = ssum[2];
    float pj = __fdiv_rn((float)HJ[tid], Sj);
    float px = __fdiv_rn(shx[tid], Sx);
    float px1 = __fdiv_rn(shx1[tid], Sx1);
    float la = (float)log((double)__fadd_rn(pj, 1e-10f));
    float lb = (float)log((double)__fadd_rn(__fmul_rn(px, px1), 1e-10f));
    sterm[tid] = __fmul_rn(pj, __fsub_rn(la, lb));
  }
  __syncthreads();
  if (tid == 0) {
    float mi = 0.0f;
    for (int i = 0; i < 100; ++i) mi = __fadd_rn(mi, sterm[i]);
    float lm = (float)log((double)mi);
    float th = tanh_emul(lm);
    float num = (float)exp(0.8);
    corr[b] = __fdiv_rn(num, th);
  }
}

// ---- mag for ALL 7 pairs, 4 consecutive hw per thread: 32 float4 loads +
// 7 float4 stores. Each pixel's per-c chain keeps the FROZEN order.
__global__ void k_mag_all(const float* __restrict__ x, const float* __restrict__ corr,
                          float* __restrict__ mag) {
  int gid = blockIdx.x * 256 + threadIdx.x;   // 0..65535 = (b, hw/4)
  int b = gid >> 14;
  int hw0 = (gid & 16383) << 2;
  int row = hw0 >> 8, col = hw0 & 255;
  int g = (row >> 3) * 32 + (col >> 3);
  int s0 = g * 64 + (row & 7) * 8 + (col & 7);  // divisible by 4
  const float cb = corr[b];
  const float4* xp = (const float4*)(x + (long long)b * TT * FRAME + hw0);
  float4 acc[7];
#pragma unroll
  for (int f = 0; f < 7; ++f) acc[f] = make_float4(0.f, 0.f, 0.f, 0.f);
  for (int c = 0; c < CC; ++c) {
    float4 v[8];
#pragma unroll
    for (int t = 0; t < 8; ++t)
      v[t] = xp[(t * CC + c) << 14];            // (t*16+c)*65536/4
#pragma unroll
    for (int f = 0; f < 7; ++f) {
      acc[f].x = __fadd_rn(acc[f].x, __fadd_rn(__fsub_rn(v[f + 1].x, v[f].x), cb));
      acc[f].y = __fadd_rn(acc[f].y, __fadd_rn(__fsub_rn(v[f + 1].y, v[f].y), cb));
      acc[f].z = __fadd_rn(acc[f].z, __fadd_rn(__fsub_rn(v[f + 1].z, v[f].z), cb));
      acc[f].w = __fadd_rn(acc[f].w, __fadd_rn(__fsub_rn(v[f + 1].w, v[f].w), cb));
    }
  }
  float4* mp = (float4*)(mag + (((long long)(b * NF)) << 16));
#pragma unroll
  for (int f = 0; f < 7; ++f)
    mp[(f << 14) + (s0 >> 2)] = acc[f];
}

// ---- top-64 stage 1: 448 blocks x ONE WAVE. Each wave owns 4096 mag
// elements in registers, finds its own 64th-largest via 32-round bitwise
// threshold search (shfl-only, zero LDS, zero barriers, zero atomics), and
// writes enc>=T candidates to its PRIVATE 128-slot range + a count word.
// Superset proof: a global-top-64 member has <=63 greater globally, hence
// <=63 in its wave's subset, hence >= wave-T -> emitted.
__global__ void __launch_bounds__(64) k_top64_local(const float* __restrict__ mag,
                                                    u64* __restrict__ cand,
                                                    u32* __restrict__ wcnt) {
  const int blk = blockIdx.x;        // 448: 16 per bf
  const int bf = blk >> 4;
  const int wid = blk & 15;
  const int lane = threadIdx.x;
  const int wbase_elem = wid * 4096;
  const float4* m4 = (const float4*)(mag + (long long)bf * SEG + wbase_elem);

  u32 e[64];
#pragma unroll
  for (int k = 0; k < 16; ++k) {
    float4 v = m4[k * 64 + lane];
    e[4 * k + 0] = encf(v.x); e[4 * k + 1] = encf(v.y);
    e[4 * k + 2] = encf(v.z); e[4 * k + 3] = encf(v.w);
  }
  u32 T = 0u;
  for (int bit = 31; bit >= 0; --bit) {
    u32 Tt = T | (1u << bit);
    u32 c = 0;
#pragma unroll
    for (int k = 0; k < 64; ++k) c += (e[k] >= Tt) ? 1u : 0u;
#pragma unroll
    for (int off = 1; off < 64; off <<= 1) c += __shfl_xor(c, off, 64);
    if (c >= 64u) T = Tt;            // uniform across wave (full butterfly)
  }

  // ballot-compacted emission into private slots [bf*2048 + wid*128 ..]
  u64* dst = cand + (long long)bf * 2048 + wid * 128;
  u32 run = 0;
  const u64 below = (lane == 0) ? 0ull : (~0ull >> (64 - lane));
#pragma unroll
  for (int k = 0; k < 64; ++k) {
    bool cnd = (e[k] >= T);
    u64 mask = __ballot(cnd);
    if (cnd) {
      u32 off = run + (u32)__popcll(mask & below);
      if (off < 128u) {
        int s = wbase_elem + (k >> 2) * 256 + lane * 4 + (k & 3);
        dst[off] = ((u64)e[k] << 32) | (u64)(0xFFFFFFFFu - (u32)s);
      }
    }
    run += (u32)__popcll(mask);
  }
  if (lane == 0) wcnt[bf * 16 + wid] = (run < 128u) ? run : 128u;
}

// ---- fused merge + graph (28 blocks x 1024).
// R15: latency-chain fixes — shfl wbase scan, per-wave compaction, 8-way
// unrolled rank merge, wave-0 shfl suffix scan in radix-169.
// All selection semantics identical (exact integers, FROZEN key order).
__global__ void __launch_bounds__(1024) k_merge_graph(const u64* __restrict__ cand,
                                                      const u32* __restrict__ wcnt,
                                                      float* __restrict__ out) {
  const int bf = blockIdx.x;
  const int tid = threadIdx.x;
  __shared__ u64 candk[2048];
  __shared__ u32 wbase[17];
  __shared__ float cy[64], cx[64];
  __shared__ float sinv[4];
  __shared__ u32 keys[4096];
  __shared__ u32 bins[256 * 32];     // bins[bin*32 + (tid&31)]
  __shared__ u32 stot[256];
  __shared__ u32 tie[4096];
  __shared__ u32 scal[4];

  // wave-parallel wbase: lanes 0-15 load counts, shfl inclusive scan
  if (tid < 64) {
    u32 v = (tid < 16) ? wcnt[bf * 16 + tid] : 0u;
#pragma unroll
    for (int off = 1; off < 16; off <<= 1) {
      u32 t = __shfl_up(v, off, 64);
      if ((int)tid - off >= 0) v += t;
    }
    if (tid < 16) wbase[tid + 1] = v;
    if (tid == 0) wbase[0] = 0u;
  }
  __syncthreads();
  // per-wave compaction: wave w loads range w (16 waves concurrent)
  {
    int w = tid >> 6, ln = tid & 63;
    u32 cnt = wbase[w + 1] - wbase[w];
    for (u32 s = ln; s < cnt; s += 64)
      candk[wbase[w] + s] = cand[(long long)bf * 2048 + w * 128 + s];
  }
  __syncthreads();
  u32 n = wbase[16];

  // exact rank merge, 8-way unrolled (8 LDS reads in flight — the R15 fix)
  for (u32 i = tid; i < n; i += 1024) {
    u64 mine = candk[i];
    int rank = 0;
    u32 j = 0;
    for (; j + 8 <= n; j += 8) {
      u64 k0 = candk[j + 0], k1 = candk[j + 1], k2 = candk[j + 2], k3 = candk[j + 3];
      u64 k4 = candk[j + 4], k5 = candk[j + 5], k6 = candk[j + 6], k7 = candk[j + 7];
      rank += (int)(k0 > mine) + (int)(k1 > mine) + (int)(k2 > mine) + (int)(k3 > mine)
            + (int)(k4 > mine) + (int)(k5 > mine) + (int)(k6 > mine) + (int)(k7 > mine);
    }
    for (; j < n; ++j) rank += (int)(candk[j] > mine);
    if (rank < 64) {
      int idx = (int)(0xFFFFFFFFu - (u32)(mine & 0xFFFFFFFFull));
      cy[rank] = (float)((idx >> 6) * 8 + 4);
      cx[rank] = (float)((idx & 63) * 8 + 4);
    }
  }
  __syncthreads();

  // mean/cov/inv — FROZEN sequential chains on thread 0 (fixed-bound loops)
  if (tid == 0) {
    float sy = 0.f, sx = 0.f;
    for (int r = 0; r < 64; ++r) sy = __fadd_rn(sy, cy[r]);
    for (int r = 0; r < 64; ++r) sx = __fadd_rn(sx, cx[r]);
    float my = __fdiv_rn(sy, 64.0f), mx = __fdiv_rn(sx, 64.0f);
    float c00 = 0.f, c01 = 0.f, c11 = 0.f;
    for (int r = 0; r < 64; ++r) {
      float dy = __fsub_rn(cy[r], my);
      float dx = __fsub_rn(cx[r], mx);
      c00 = __fadd_rn(c00, __fmul_rn(dy, dy));
      c01 = __fadd_rn(c01, __fmul_rn(dy, dx));
      c11 = __fadd_rn(c11, __fmul_rn(dx, dx));
    }
    c00 = __fdiv_rn(c00, 63.0f); c01 = __fdiv_rn(c01, 63.0f); c11 = __fdiv_rn(c11, 63.0f);
    c00 = __fadd_rn(c00, 1e-6f); c11 = __fadd_rn(c11, 1e-6f);
    double det = (double)c00 * (double)c11 - (double)c01 * (double)c01;
    sinv[0] = (float)((double)c11 / det);
    sinv[1] = (float)(-(double)c01 / det);
    sinv[2] = sinv[1];
    sinv[3] = (float)((double)c00 / det);
  }
  __syncthreads();

  // maha keys + zero output — FROZEN arithmetic, order-independent
  float i00 = sinv[0], i01 = sinv[1], i10 = sinv[2], i11 = sinv[3];
  long long obase = (long long)bf * 4096;
  for (int ee = tid; ee < 4096; ee += 1024) {
    int q = ee >> 6, r = ee & 63;
    float d0 = __fsub_rn(cy[r], cy[q]);
    float d1 = __fsub_rn(cx[r], cx[q]);
    float v0 = __fadd_rn(__fadd_rn(0.0f, __fmul_rn(d0, i00)), __fmul_rn(d1, i10));
    float v1 = __fadd_rn(__fadd_rn(0.0f, __fmul_rn(d0, i01)), __fmul_rn(d1, i11));
    float p0 = __fmul_rn(v0, d0);
    float p1 = __fmul_rn(v1, d1);
    float s0 = __fsqrt_rn(p0);
    float s1 = __fsqrt_rn(p1);
    float mh = __fadd_rn(__fadd_rn(0.0f, s0), s1);
    u32 key;
    if (mh != mh) key = 0xFFFFFFFFu;   // NaN first (POLICY A, FROZEN)
    else key = encf(-mh);
    keys[ee] = key;
    out[obase + ee] = 0.0f;
  }
  __syncthreads();

  // radix-select top-169: 32-way replicated bins + wave-0 shfl suffix scan
  u32 prefix = 0u, need = 169u;
  for (int pass = 0; pass < 4; ++pass) {
    int shift = 24 - pass * 8;
    if (tid == 0) scal[2] = 0u;
    for (int i = tid; i < 8192; i += 1024) bins[i] = 0u;
    __syncthreads();
    for (int k = 0; k < 4; ++k) {
      u32 ky = keys[tid + (k << 10)];
      bool ok = (pass == 0) || ((ky >> (shift + 8)) == (prefix >> (shift + 8)));
      if (ok) atomicAdd(&bins[(((ky >> shift) & 0xFFu) << 5) + (tid & 31)], 1u);
    }
    __syncthreads();
    if (tid < 256) {                       // per-bin totals (rotated reads)
      u32 s = 0;
#pragma unroll
      for (int c = 0; c < 32; ++c) s += bins[(tid << 5) + ((c + tid) & 31)];
      stot[tid] = s;
    }
    __syncthreads();
    // wave 0: suffix-inclusive scan over 256 bins, all-shfl (zero barriers)
    if (tid < 64) {
      int l = tid;
      u32 t0 = stot[4 * l + 0], t1 = stot[4 * l + 1],
          t2 = stot[4 * l + 2], t3 = stot[4 * l + 3];
      u32 b3 = t3;
      u32 b2 = t2 + b3;
      u32 b1 = t1 + b2;
      u32 b0 = t0 + b1;                    // intra-quad suffix sums
      u32 incl = b0;                       // quad sum
#pragma unroll
      for (int off = 1; off < 64; off <<= 1) {
        u32 t = __shfl_down(incl, off, 64);
        if (l + off < 64) incl += t;
      }
      u32 excl = incl - b0;                // sum of quads strictly after l
      u32 si0 = b0 + excl, si1 = b1 + excl, si2 = b2 + excl, si3 = b3 + excl;
      // cut: max bin d with suffix_incl(d) >= need  (exactly one fires)
      if (si0 >= need && si1 < need) { scal[0] = prefix | ((u32)(4 * l + 0) << shift); scal[1] = need - si1; }
      if (si1 >= need && si2 < need) { scal[0] = prefix | ((u32)(4 * l + 1) << shift); scal[1] = need - si2; }
      if (si2 >= need && si3 < need) { scal[0] = prefix | ((u32)(4 * l + 2) << shift); scal[1] = need - si3; }
      if (si3 >= need && excl < need) { scal[0] = prefix | ((u32)(4 * l + 3) << shift); scal[1] = need - excl; }
    }
    __syncthreads();
    prefix = scal[0]; need = scal[1];
    __syncthreads();
  }
  for (int k = 0; k < 4; ++k) {
    int ee = tid + (k << 10);
    u32 ky = keys[ee];
    if (ky > prefix) out[obase + ee] = 1.0f;
    else if (ky == prefix) {
      u32 p = atomicAdd(&scal[2], 1u);
      tie[p] = (u32)ee;
    }
  }
  __syncthreads();
  int tc = (int)scal[2];
  for (int i = tid; i < tc; i += 1024) {
    u32 ei = tie[i];
    int rank = 0;
    for (int j = 0; j < tc; ++j) rank += (tie[j] < ei);
    if (rank < (int)need) out[obase + ei] = 1.0f;
  }
}

extern "C" void kernel_launch(void* const* d_in, const int* in_sizes, int n_in,
                              void* d_out, int out_size, void* d_ws, size_t ws_size,
                              hipStream_t stream) {
  if (ws_size < (size_t)WS_NEED) return;
  const float* x = (const float*)d_in[0];
  float* out = (float*)d_out;
  char* ws = (char*)d_ws;
  u32* mm = (u32*)(ws + WS_MM);
  float* corr = (float*)(ws + WS_CORR);
  u32* wcnt = (u32*)(ws + WS_WCNT);
  float* mag = (float*)(ws + WS_MAG);
  u32* mmpart = (u32*)(ws + WS_MMPART);   // overlaid on mag region
  u32* histc = (u32*)(ws + WS_HISTC);     // overlaid on mag region
  u64* cand = (u64*)d_out;                // consumed by k_merge_graph

  hipLaunchKernelGGL(k_minmax_pass, dim3(2048), dim3(256), 0, stream, x, mmpart);
  hipLaunchKernelGGL(k_mm_reduce, dim3(4), dim3(256), 0, stream, mmpart, mm);
  hipLaunchKernelGGL(k_hist_pass, dim3(2048), dim3(256), 0, stream, x, mm, histc);
  hipLaunchKernelGGL(k_corr, dim3(4), dim3(256), 0, stream, histc, corr);
  hipLaunchKernelGGL(k_mag_all, dim3(256), dim3(256), 0, stream, x, corr, mag);
  hipLaunchKernelGGL(k_top64_local, dim3(448), dim3(64), 0, stream, mag, cand, wcnt);
  hipLaunchKernelGGL(k_merge_graph, dim3(28), dim3(1024), 0, stream, cand, wcnt, out);
}

// Round 16
// 184.750 us; speedup vs baseline: 1.3684x; 1.0835x over previous
//
#include <hip/hip_runtime.h>
#include <stdint.h>

// ============================================================================
// Motion_Relation_Mining — bit-exact replication of the JAX (CPU) reference.
//
// FROZEN (verified passing R0-R15, absmax 0.0): all f32 op sequences,
// NAN_POLICY_A, FMA-tanh, sequential reduce orders, selection key
// (enc(value)<<32)|~idx i.e. (value desc, index asc).
//
// R2: two-stage reductions replaced contended global atomics.
// R3: k_corr parallelized (scratch -> LDS, logs 100-wide).
// R4 (FAILED): ballot match-any — unroll spilled enc[] to scratch.
// R8: block-wide bitwise threshold search — barrier convoy (97us).
// R9: wave-autonomous threshold search (shfl-only, zero barriers).
// R10: k_mag_all (x read once), non-atomic hist partials, fused corr.
// R11 (FAILED): fusing top64 into the 28-block kernel throttled it.
// R12: 448x64 top64 + 28-block merge_graph.
// R13/R14: radix-169 32-way replicated bins + parallel scan.
// R15 (PARTIAL): 8-way unroll of the O(n^2) rank merge — total only -5us;
//      merge_graph still ~70us. The 1.1M dependent-LDS-read structure
//      survives unrolling.
// R16: rank merge DELETED. Phase 2 now uses the proven radix-select
//      (4 passes on enc hi-32, replicated bins + shfl suffix scan) to find
//      the 64-member set, then a FIXED-BOUND 64x64 unrolled broadcast rank.
//      Same key, same tie rule (smallest idx), exact integers -> bit-exact.
// ============================================================================

typedef unsigned int u32;
typedef unsigned long long u64;

// sizes
#define BB 4
#define TT 8
#define CC 16
#define HWN 65536              // H*W
#define NF 7
#define FRAME 1048576LL        // C*H*W
#define NELF 7340032.0f        // nf*C*H*W per batch (exact in f32)
#define NPAIR 28
#define SEG 65536

// ws layout (bytes)
#define WS_MM 0                // u32[24] final min/max (encoded)
#define WS_CORR 128            // float[4]
#define WS_WCNT 144            // u32[28][16] per-wave candidate counts
#define WS_MAG 16384           // float[28][65536]
// overlaid inside WS_MAG region — fully consumed before k_mag_all writes:
#define WS_MMPART (WS_MAG)            // u32[2048][6]  = 48 KiB
#define WS_HISTC  (WS_MAG + 65536)    // u32[2048][300] = 2.4 MiB
#define WS_NEED (16384 + 28LL*65536*4)
// candidate buffer lives in d_out: per bf a private 16KB range of
// 16 waves x 128 u64 slots. k_merge_graph consumes it (into LDS) before
// overwriting the same range with the output zeros/ones.

__device__ __forceinline__ u32 encf(float f) {
  u32 u = __float_as_uint(f);
  return (u & 0x80000000u) ? ~u : (u | 0x80000000u);
}
__device__ __forceinline__ float decf(u32 e) {
  u32 u = (e & 0x80000000u) ? (e ^ 0x80000000u) : ~e;
  return __uint_as_float(u);
}

// ---- single pass over frames: per-batch min/max of x_t, x_t1, x_t*x_t1.
// float4 loads; min/max order-free; product elementwise -> exact.
__global__ void k_minmax_pass(const float* __restrict__ x, u32* __restrict__ part) {
  const int blk = blockIdx.x;            // 2048 blocks: 512 per batch
  const int b = blk >> 9;
  const long long w0 = (long long)(blk & 511) * 2048;
  const int tid = threadIdx.x;
  u32 mn0 = 0xFFFFFFFFu, mx0 = 0u, mn1 = 0xFFFFFFFFu, mx1 = 0u,
      mnp = 0xFFFFFFFFu, mxp = 0u;
  float4 pv0, pv1;
  for (int t = 0; t < 8; ++t) {
    const float4* fp = (const float4*)(x + ((long long)(b * TT + t)) * FRAME + w0);
    float4 v0 = fp[tid];
    float4 v1 = fp[tid + 256];
#define MM_COMP(vc, pc)                                                     \
    {                                                                       \
      u32 ev = encf(vc);                                                    \
      if (t < 7) { mn0 = min(mn0, ev); mx0 = max(mx0, ev); }                \
      if (t > 0) {                                                          \
        mn1 = min(mn1, ev); mx1 = max(mx1, ev);                             \
        u32 ep = encf(__fmul_rn(pc, vc));                                   \
        mnp = min(mnp, ep); mxp = max(mxp, ep);                             \
      }                                                                     \
    }
    MM_COMP(v0.x, pv0.x) MM_COMP(v0.y, pv0.y) MM_COMP(v0.z, pv0.z) MM_COMP(v0.w, pv0.w)
    MM_COMP(v1.x, pv1.x) MM_COMP(v1.y, pv1.y) MM_COMP(v1.z, pv1.z) MM_COMP(v1.w, pv1.w)
#undef MM_COMP
    pv0 = v0; pv1 = v1;
  }
  __shared__ u32 sm[6][256];
  sm[0][tid] = mn0; sm[1][tid] = mx0; sm[2][tid] = mn1;
  sm[3][tid] = mx1; sm[4][tid] = mnp; sm[5][tid] = mxp;
  __syncthreads();
  for (int st = 128; st > 0; st >>= 1) {
    if (tid < st) {
      sm[0][tid] = min(sm[0][tid], sm[0][tid + st]);
      sm[1][tid] = max(sm[1][tid], sm[1][tid + st]);
      sm[2][tid] = min(sm[2][tid], sm[2][tid + st]);
      sm[3][tid] = max(sm[3][tid], sm[3][tid + st]);
      sm[4][tid] = min(sm[4][tid], sm[4][tid + st]);
      sm[5][tid] = max(sm[5][tid], sm[5][tid + st]);
    }
    __syncthreads();
  }
  if (tid == 0) {
    u32* o = part + blk * 6;
    o[0] = sm[0][0]; o[1] = sm[1][0]; o[2] = sm[2][0];
    o[3] = sm[3][0]; o[4] = sm[4][0]; o[5] = sm[5][0];
  }
}

// 4 blocks (one per batch): reduce 512 partials -> mm[b*6..]
__global__ void k_mm_reduce(const u32* __restrict__ part, u32* __restrict__ mm) {
  const int b = blockIdx.x;
  const int tid = threadIdx.x;
  const u32* p0 = part + (b * 512 + tid) * 6;
  const u32* p1 = p0 + 256 * 6;
  __shared__ u32 sm[6][256];
  sm[0][tid] = min(p0[0], p1[0]); sm[1][tid] = max(p0[1], p1[1]);
  sm[2][tid] = min(p0[2], p1[2]); sm[3][tid] = max(p0[3], p1[3]);
  sm[4][tid] = min(p0[4], p1[4]); sm[5][tid] = max(p0[5], p1[5]);
  __syncthreads();
  for (int st = 128; st > 0; st >>= 1) {
    if (tid < st) {
      sm[0][tid] = min(sm[0][tid], sm[0][tid + st]);
      sm[1][tid] = max(sm[1][tid], sm[1][tid + st]);
      sm[2][tid] = min(sm[2][tid], sm[2][tid + st]);
      sm[3][tid] = max(sm[3][tid], sm[3][tid + st]);
      sm[4][tid] = min(sm[4][tid], sm[4][tid + st]);
      sm[5][tid] = max(sm[5][tid], sm[5][tid + st]);
    }
    __syncthreads();
  }
  if (tid == 0)
    for (int i = 0; i < 6; ++i) mm[b * 6 + i] = sm[i][0];
}

__device__ __forceinline__ int bin_of(float v, float vmin, float den) {
  float tt = __fsub_rn(v, vmin);
  float q = __fdiv_rn(tt, den);
  float z = __fmul_rn(q, 100.0f);
  z = fminf(fmaxf(z, 0.0f), 99.0f);
  return (int)z;
}

// ---- single pass over frames: float4 loads + 32-way lane-replicated
// LDS sub-histograms, flushed NON-atomically (rotated conflict-free reads)
// to the block's private 300-u32 partial.
__global__ void k_hist_pass(const float* __restrict__ x, const u32* __restrict__ mm,
                            u32* __restrict__ histc) {
  __shared__ u32 h[300 * 32];            // h[bin*32 + (tid&31)]
  for (int i = threadIdx.x; i < 9600; i += 256) h[i] = 0u;
  __syncthreads();
  const int blk = blockIdx.x;
  const int b = blk >> 9;
  const long long w0 = (long long)(blk & 511) * 2048;
  const int tid = threadIdx.x;
  const int sub = tid & 31;
  float mn_t = decf(mm[6 * b + 0]), den_t = __fsub_rn(decf(mm[6 * b + 1]), decf(mm[6 * b + 0]));
  float mn_1 = decf(mm[6 * b + 2]), den_1 = __fsub_rn(decf(mm[6 * b + 3]), decf(mm[6 * b + 2]));
  float mn_p = decf(mm[6 * b + 4]), den_p = __fsub_rn(decf(mm[6 * b + 5]), decf(mm[6 * b + 4]));
  float4 pv0, pv1;
  for (int t = 0; t < 8; ++t) {
    const float4* fp = (const float4*)(x + ((long long)(b * TT + t)) * FRAME + w0);
    float4 v0 = fp[tid];
    float4 v1 = fp[tid + 256];
#define HH_COMP(vc, pc)                                                       \
    {                                                                         \
      if (t < 7) atomicAdd(&h[bin_of(vc, mn_t, den_t) * 32 + sub], 1u);       \
      if (t > 0) {                                                            \
        atomicAdd(&h[(100 + bin_of(vc, mn_1, den_1)) * 32 + sub], 1u);        \
        float p = __fmul_rn(pc, vc);                                          \
        atomicAdd(&h[(200 + bin_of(p, mn_p, den_p)) * 32 + sub], 1u);         \
      }                                                                       \
    }
    HH_COMP(v0.x, pv0.x) HH_COMP(v0.y, pv0.y) HH_COMP(v0.z, pv0.z) HH_COMP(v0.w, pv0.w)
    HH_COMP(v1.x, pv1.x) HH_COMP(v1.y, pv1.y) HH_COMP(v1.z, pv1.z) HH_COMP(v1.w, pv1.w)
#undef HH_COMP
    pv0 = v0; pv1 = v1;
  }
  __syncthreads();
  u32* dst = histc + blk * 300;
  for (int i = threadIdx.x; i < 300; i += 256) {
    u32 s = 0;
#pragma unroll
    for (int c = 0; c < 32; ++c)
      s += h[i * 32 + ((c + i) & 31)];   // rotated: conflict-free banks
    dst[i] = s;                          // non-atomic private partial
  }
}

// Eigen/XLA fast-tanh rational interpolant (FMA form) — FROZEN
__device__ float tanh_emul(float a) {
  const float kClamp = 7.90531110763549805f;
  float xx = fminf(fmaxf(a, -kClamp), kClamp);
  float x2 = __fmul_rn(xx, xx);
  float p = __fmaf_rn(x2, -2.76076847742355e-16f, 2.00018790482477e-13f);
  p = __fmaf_rn(x2, p, -8.60467152213735e-11f);
  p = __fmaf_rn(x2, p, 5.12229709037114e-08f);
  p = __fmaf_rn(x2, p, 1.48572235717979e-05f);
  p = __fmaf_rn(x2, p, 6.37261928875436e-04f);
  p = __fmaf_rn(x2, p, 4.89352455891786e-03f);
  p = __fmul_rn(xx, p);
  float q = __fmaf_rn(x2, 1.19825839466702e-06f, 1.18534705686654e-04f);
  q = __fmaf_rn(x2, q, 2.26843463243900e-03f);
  q = __fmaf_rn(x2, q, 4.89352518554385e-03f);
  float r = __fdiv_rn(p, q);
  if (fabsf(a) < 0.0004f) r = a;
  return r;
}

// ---- per-batch: sum 512 partial histograms (8-way ILP, exact ints),
// then mi/corr with FROZEN sequential chains on thread 0.
__global__ void __launch_bounds__(256) k_corr(const u32* __restrict__ histc,
                                              float* __restrict__ corr) {
  const int b = blockIdx.x;
  const int tid = threadIdx.x;
  __shared__ u32 shist[300];
  __shared__ float shx[100], shx1[100], sterm[100];
  __shared__ float ssum[3];
  for (int i = tid; i < 300; i += 256) {
    const u32* src = histc + (long long)(b * 512) * 300 + i;
    u32 s0 = 0, s1 = 0, s2 = 0, s3 = 0, s4 = 0, s5 = 0, s6 = 0, s7 = 0;
    for (int c = 0; c < 512; c += 8) {   // 8 independent load chains (ILP)
      s0 += src[(c + 0) * 300]; s1 += src[(c + 1) * 300];
      s2 += src[(c + 2) * 300]; s3 += src[(c + 3) * 300];
      s4 += src[(c + 4) * 300]; s5 += src[(c + 5) * 300];
      s6 += src[(c + 6) * 300]; s7 += src[(c + 7) * 300];
    }
    shist[i] = ((s0 + s1) + (s2 + s3)) + ((s4 + s5) + (s6 + s7));
  }
  __syncthreads();
  const u32* HX = shist;
  const u32* HX1 = shist + 100;
  const u32* HJ = shist + 200;
  if (tid < 100) {
    shx[tid] = __fdiv_rn((float)HX[tid], NELF);
    shx1[tid] = __fdiv_rn((float)HX1[tid], NELF);
  }
  __syncthreads();
  if (tid == 0) {
    float Sj = 0.0f;
    for (int i = 0; i < 100; ++i) Sj = __fadd_rn(Sj, (float)HJ[i]);
    float Sx = 0.0f, Sx1 = 0.0f;
    for (int i = 0; i < 100; ++i) Sx = __fadd_rn(Sx, shx[i]);
    for (int i = 0; i < 100; ++i) Sx1 = __fadd_rn(Sx1, shx1[i]);
    ssum[0] = Sj; ssum[1] = Sx; ssum[2] = Sx1;
  }
  __syncthreads();
  if (tid < 100) {
    float Sj = ssum[0], Sx = ssum[1], Sx1 = ssum[2];
    float pj = __fdiv_rn((float)HJ[tid], Sj);
    float px = __fdiv_rn(shx[tid], Sx);
    float px1 = __fdiv_rn(shx1[tid], Sx1);
    float la = (float)log((double)__fadd_rn(pj, 1e-10f));
    float lb = (float)log((double)__fadd_rn(__fmul_rn(px, px1), 1e-10f));
    sterm[tid] = __fmul_rn(pj, __fsub_rn(la, lb));
  }
  __syncthreads();
  if (tid == 0) {
    float mi = 0.0f;
    for (int i = 0; i < 100; ++i) mi = __fadd_rn(mi, sterm[i]);
    float lm = (float)log((double)mi);
    float th = tanh_emul(lm);
    float num = (float)exp(0.8);
    corr[b] = __fdiv_rn(num, th);
  }
}

// ---- mag for ALL 7 pairs, 4 consecutive hw per thread: 32 float4 loads +
// 7 float4 stores. Each pixel's per-c chain keeps the FROZEN order.
__global__ void k_mag_all(const float* __restrict__ x, const float* __restrict__ corr,
                          float* __restrict__ mag) {
  int gid = blockIdx.x * 256 + threadIdx.x;   // 0..65535 = (b, hw/4)
  int b = gid >> 14;
  int hw0 = (gid & 16383) << 2;
  int row = hw0 >> 8, col = hw0 & 255;
  int g = (row >> 3) * 32 + (col >> 3);
  int s0 = g * 64 + (row & 7) * 8 + (col & 7);  // divisible by 4
  const float cb = corr[b];
  const float4* xp = (const float4*)(x + (long long)b * TT * FRAME + hw0);
  float4 acc[7];
#pragma unroll
  for (int f = 0; f < 7; ++f) acc[f] = make_float4(0.f, 0.f, 0.f, 0.f);
  for (int c = 0; c < CC; ++c) {
    float4 v[8];
#pragma unroll
    for (int t = 0; t < 8; ++t)
      v[t] = xp[(t * CC + c) << 14];            // (t*16+c)*65536/4
#pragma unroll
    for (int f = 0; f < 7; ++f) {
      acc[f].x = __fadd_rn(acc[f].x, __fadd_rn(__fsub_rn(v[f + 1].x, v[f].x), cb));
      acc[f].y = __fadd_rn(acc[f].y, __fadd_rn(__fsub_rn(v[f + 1].y, v[f].y), cb));
      acc[f].z = __fadd_rn(acc[f].z, __fadd_rn(__fsub_rn(v[f + 1].z, v[f].z), cb));
      acc[f].w = __fadd_rn(acc[f].w, __fadd_rn(__fsub_rn(v[f + 1].w, v[f].w), cb));
    }
  }
  float4* mp = (float4*)(mag + (((long long)(b * NF)) << 16));
#pragma unroll
  for (int f = 0; f < 7; ++f)
    mp[(f << 14) + (s0 >> 2)] = acc[f];
}

// ---- top-64 stage 1: 448 blocks x ONE WAVE. Each wave owns 4096 mag
// elements in registers, finds its own 64th-largest via 32-round bitwise
// threshold search (shfl-only, zero LDS, zero barriers, zero atomics), and
// writes enc>=T candidates to its PRIVATE 128-slot range + a count word.
// Superset proof: a global-top-64 member has <=63 greater globally, hence
// <=63 in its wave's subset, hence >= wave-T -> emitted.
__global__ void __launch_bounds__(64) k_top64_local(const float* __restrict__ mag,
                                                    u64* __restrict__ cand,
                                                    u32* __restrict__ wcnt) {
  const int blk = blockIdx.x;        // 448: 16 per bf
  const int bf = blk >> 4;
  const int wid = blk & 15;
  const int lane = threadIdx.x;
  const int wbase_elem = wid * 4096;
  const float4* m4 = (const float4*)(mag + (long long)bf * SEG + wbase_elem);

  u32 e[64];
#pragma unroll
  for (int k = 0; k < 16; ++k) {
    float4 v = m4[k * 64 + lane];
    e[4 * k + 0] = encf(v.x); e[4 * k + 1] = encf(v.y);
    e[4 * k + 2] = encf(v.z); e[4 * k + 3] = encf(v.w);
  }
  u32 T = 0u;
  for (int bit = 31; bit >= 0; --bit) {
    u32 Tt = T | (1u << bit);
    u32 c = 0;
#pragma unroll
    for (int k = 0; k < 64; ++k) c += (e[k] >= Tt) ? 1u : 0u;
#pragma unroll
    for (int off = 1; off < 64; off <<= 1) c += __shfl_xor(c, off, 64);
    if (c >= 64u) T = Tt;            // uniform across wave (full butterfly)
  }

  // ballot-compacted emission into private slots [bf*2048 + wid*128 ..]
  u64* dst = cand + (long long)bf * 2048 + wid * 128;
  u32 run = 0;
  const u64 below = (lane == 0) ? 0ull : (~0ull >> (64 - lane));
#pragma unroll
  for (int k = 0; k < 64; ++k) {
    bool cnd = (e[k] >= T);
    u64 mask = __ballot(cnd);
    if (cnd) {
      u32 off = run + (u32)__popcll(mask & below);
      if (off < 128u) {
        int s = wbase_elem + (k >> 2) * 256 + lane * 4 + (k & 3);
        dst[off] = ((u64)e[k] << 32) | (u64)(0xFFFFFFFFu - (u32)s);
      }
    }
    run += (u32)__popcll(mask);
  }
  if (lane == 0) wcnt[bf * 16 + wid] = (run < 128u) ? run : 128u;
}

// ---- fused merge + graph (28 blocks x 1024).
// Phase 2 (R16): radix-select top-64 on candidate enc (hi-32) using the
// proven replicated-bin + shfl-suffix-scan machinery, then a fixed-bound
// 64x64 unrolled broadcast rank. Replaces the O(n^2) rank merge.
// Phases 3-5: FROZEN cov/inv/maha/radix-169.
__global__ void __launch_bounds__(1024) k_merge_graph(const u64* __restrict__ cand,
                                                      const u32* __restrict__ wcnt,
                                                      float* __restrict__ out) {
  const int bf = blockIdx.x;
  const int tid = threadIdx.x;
  __shared__ u64 candk[2048];
  __shared__ u64 sel64[64];
  __shared__ u32 wbase[17];
  __shared__ float cy[64], cx[64];
  __shared__ float sinv[4];
  __shared__ u32 keys[4096];
  __shared__ u32 bins[256 * 32];     // bins[bin*32 + (tid&31)]
  __shared__ u32 stot[256];
  __shared__ u32 tie[4096];
  __shared__ u32 scal[4];

  // wave-parallel wbase: lanes 0-15 load counts, shfl inclusive scan
  if (tid < 64) {
    u32 v = (tid < 16) ? wcnt[bf * 16 + tid] : 0u;
#pragma unroll
    for (int off = 1; off < 16; off <<= 1) {
      u32 t = __shfl_up(v, off, 64);
      if ((int)tid - off >= 0) v += t;
    }
    if (tid < 16) wbase[tid + 1] = v;
    if (tid == 0) wbase[0] = 0u;
  }
  __syncthreads();
  // per-wave compaction: wave w loads range w (16 waves concurrent)
  {
    int w = tid >> 6, ln = tid & 63;
    u32 cnt = wbase[w + 1] - wbase[w];
    for (u32 s = ln; s < cnt; s += 64)
      candk[wbase[w] + s] = cand[(long long)bf * 2048 + w * 128 + s];
  }
  __syncthreads();
  u32 n = wbase[16];

  // phase 2 (R16): radix-select the 64th-largest enc among candidates
  u32 prefix2 = 0u, need2 = 64u;
  for (int pass = 0; pass < 4; ++pass) {
    int shift = 24 - pass * 8;
    for (int i = tid; i < 8192; i += 1024) bins[i] = 0u;
    __syncthreads();
    for (u32 i = tid; i < n; i += 1024) {
      u32 e = (u32)(candk[i] >> 32);
      bool ok = (pass == 0) || ((e >> (shift + 8)) == (prefix2 >> (shift + 8)));
      if (ok) atomicAdd(&bins[(((e >> shift) & 0xFFu) << 5) + (tid & 31)], 1u);
    }
    __syncthreads();
    if (tid < 256) {
      u32 s = 0;
#pragma unroll
      for (int c = 0; c < 32; ++c) s += bins[(tid << 5) + ((c + tid) & 31)];
      stot[tid] = s;
    }
    __syncthreads();
    if (tid < 64) {
      int l = tid;
      u32 t0 = stot[4 * l + 0], t1 = stot[4 * l + 1],
          t2 = stot[4 * l + 2], t3 = stot[4 * l + 3];
      u32 b3 = t3, b2 = t2 + b3, b1 = t1 + b2, b0 = t0 + b1;
      u32 incl = b0;
#pragma unroll
      for (int off = 1; off < 64; off <<= 1) {
        u32 t = __shfl_down(incl, off, 64);
        if (l + off < 64) incl += t;
      }
      u32 excl = incl - b0;
      u32 si0 = b0 + excl, si1 = b1 + excl, si2 = b2 + excl, si3 = b3 + excl;
      if (si0 >= need2 && si1 < need2) { scal[0] = prefix2 | ((u32)(4 * l + 0) << shift); scal[1] = need2 - si1; }
      if (si1 >= need2 && si2 < need2) { scal[0] = prefix2 | ((u32)(4 * l + 1) << shift); scal[1] = need2 - si2; }
      if (si2 >= need2 && si3 < need2) { scal[0] = prefix2 | ((u32)(4 * l + 2) << shift); scal[1] = need2 - si3; }
      if (si3 >= need2 && excl < need2) { scal[0] = prefix2 | ((u32)(4 * l + 3) << shift); scal[1] = need2 - excl; }
    }
    __syncthreads();
    prefix2 = scal[0]; need2 = scal[1];
    __syncthreads();
  }
  // collect: enc > prefix2 definite; enc == prefix2 -> smallest-idx ties
  if (tid == 0) { scal[2] = 0u; scal[3] = 0u; }
  __syncthreads();
  for (u32 i = tid; i < n; i += 1024) {
    u64 key = candk[i];
    u32 e = (u32)(key >> 32);
    if (e > prefix2) {
      u32 p = atomicAdd(&scal[3], 1u);
      sel64[p] = key;
    } else if (e == prefix2) {
      u32 p = atomicAdd(&scal[2], 1u);
      tie[p] = (u32)(key & 0xFFFFFFFFull);   // ~s (larger = smaller idx)
    }
  }
  __syncthreads();
  {
    int tc2 = (int)scal[2];
    for (int i = tid; i < tc2; i += 1024) {
      u32 mine = tie[i];
      int r = 0, j = 0;
      for (; j + 8 <= tc2; j += 8) {
        u32 a0 = tie[j], a1 = tie[j + 1], a2 = tie[j + 2], a3 = tie[j + 3];
        u32 a4 = tie[j + 4], a5 = tie[j + 5], a6 = tie[j + 6], a7 = tie[j + 7];
        r += (int)(a0 > mine) + (int)(a1 > mine) + (int)(a2 > mine) + (int)(a3 > mine)
           + (int)(a4 > mine) + (int)(a5 > mine) + (int)(a6 > mine) + (int)(a7 > mine);
      }
      for (; j < tc2; ++j) r += (int)(tie[j] > mine);
      if (r < (int)need2) {
        u32 p = atomicAdd(&scal[3], 1u);
        sel64[p] = ((u64)prefix2 << 32) | (u64)mine;
      }
    }
  }
  __syncthreads();
  // exact rank among the 64 (fixed bound -> fully unrolled broadcast reads)
  if (tid < 64) {
    u64 mine = sel64[tid];
    int rank = 0;
#pragma unroll
    for (int j = 0; j < 64; ++j) rank += (sel64[j] > mine) ? 1 : 0;
    int idx = (int)(0xFFFFFFFFu - (u32)(mine & 0xFFFFFFFFull));
    cy[rank] = (float)((idx >> 6) * 8 + 4);
    cx[rank] = (float)((idx & 63) * 8 + 4);
  }
  __syncthreads();

  // mean/cov/inv — FROZEN sequential chains on thread 0 (fixed-bound loops)
  if (tid == 0) {
    float sy = 0.f, sx = 0.f;
    for (int r = 0; r < 64; ++r) sy = __fadd_rn(sy, cy[r]);
    for (int r = 0; r < 64; ++r) sx = __fadd_rn(sx, cx[r]);
    float my = __fdiv_rn(sy, 64.0f), mx = __fdiv_rn(sx, 64.0f);
    float c00 = 0.f, c01 = 0.f, c11 = 0.f;
    for (int r = 0; r < 64; ++r) {
      float dy = __fsub_rn(cy[r], my);
      float dx = __fsub_rn(cx[r], mx);
      c00 = __fadd_rn(c00, __fmul_rn(dy, dy));
      c01 = __fadd_rn(c01, __fmul_rn(dy, dx));
      c11 = __fadd_rn(c11, __fmul_rn(dx, dx));
    }
    c00 = __fdiv_rn(c00, 63.0f); c01 = __fdiv_rn(c01, 63.0f); c11 = __fdiv_rn(c11, 63.0f);
    c00 = __fadd_rn(c00, 1e-6f); c11 = __fadd_rn(c11, 1e-6f);
    double det = (double)c00 * (double)c11 - (double)c01 * (double)c01;
    sinv[0] = (float)((double)c11 / det);
    sinv[1] = (float)(-(double)c01 / det);
    sinv[2] = sinv[1];
    sinv[3] = (float)((double)c00 / det);
  }
  __syncthreads();

  // maha keys + zero output — FROZEN arithmetic, order-independent
  float i00 = sinv[0], i01 = sinv[1], i10 = sinv[2], i11 = sinv[3];
  long long obase = (long long)bf * 4096;
  for (int ee = tid; ee < 4096; ee += 1024) {
    int q = ee >> 6, r = ee & 63;
    float d0 = __fsub_rn(cy[r], cy[q]);
    float d1 = __fsub_rn(cx[r], cx[q]);
    float v0 = __fadd_rn(__fadd_rn(0.0f, __fmul_rn(d0, i00)), __fmul_rn(d1, i10));
    float v1 = __fadd_rn(__fadd_rn(0.0f, __fmul_rn(d0, i01)), __fmul_rn(d1, i11));
    float p0 = __fmul_rn(v0, d0);
    float p1 = __fmul_rn(v1, d1);
    float s0 = __fsqrt_rn(p0);
    float s1 = __fsqrt_rn(p1);
    float mh = __fadd_rn(__fadd_rn(0.0f, s0), s1);
    u32 key;
    if (mh != mh) key = 0xFFFFFFFFu;   // NaN first (POLICY A, FROZEN)
    else key = encf(-mh);
    keys[ee] = key;
    out[obase + ee] = 0.0f;
  }
  __syncthreads();

  // radix-select top-169: 32-way replicated bins + wave-0 shfl suffix scan
  u32 prefix = 0u, need = 169u;
  for (int pass = 0; pass < 4; ++pass) {
    int shift = 24 - pass * 8;
    if (tid == 0) scal[2] = 0u;
    for (int i = tid; i < 8192; i += 1024) bins[i] = 0u;
    __syncthreads();
    for (int k = 0; k < 4; ++k) {
      u32 ky = keys[tid + (k << 10)];
      bool ok = (pass == 0) || ((ky >> (shift + 8)) == (prefix >> (shift + 8)));
      if (ok) atomicAdd(&bins[(((ky >> shift) & 0xFFu) << 5) + (tid & 31)], 1u);
    }
    __syncthreads();
    if (tid < 256) {                       // per-bin totals (rotated reads)
      u32 s = 0;
#pragma unroll
      for (int c = 0; c < 32; ++c) s += bins[(tid << 5) + ((c + tid) & 31)];
      stot[tid] = s;
    }
    __syncthreads();
    // wave 0: suffix-inclusive scan over 256 bins, all-shfl (zero barriers)
    if (tid < 64) {
      int l = tid;
      u32 t0 = stot[4 * l + 0], t1 = stot[4 * l + 1],
          t2 = stot[4 * l + 2], t3 = stot[4 * l + 3];
      u32 b3 = t3;
      u32 b2 = t2 + b3;
      u32 b1 = t1 + b2;
      u32 b0 = t0 + b1;                    // intra-quad suffix sums
      u32 incl = b0;                       // quad sum
#pragma unroll
      for (int off = 1; off < 64; off <<= 1) {
        u32 t = __shfl_down(incl, off, 64);
        if (l + off < 64) incl += t;
      }
      u32 excl = incl - b0;                // sum of quads strictly after l
      u32 si0 = b0 + excl, si1 = b1 + excl, si2 = b2 + excl, si3 = b3 + excl;
      if (si0 >= need && si1 < need) { scal[0] = prefix | ((u32)(4 * l + 0) << shift); scal[1] = need - si1; }
      if (si1 >= need && si2 < need) { scal[0] = prefix | ((u32)(4 * l + 1) << shift); scal[1] = need - si2; }
      if (si2 >= need && si3 < need) { scal[0] = prefix | ((u32)(4 * l + 2) << shift); scal[1] = need - si3; }
      if (si3 >= need && excl < need) { scal[0] = prefix | ((u32)(4 * l + 3) << shift); scal[1] = need - excl; }
    }
    __syncthreads();
    prefix = scal[0]; need = scal[1];
    __syncthreads();
  }
  for (int k = 0; k < 4; ++k) {
    int ee = tid + (k << 10);
    u32 ky = keys[ee];
    if (ky > prefix) out[obase + ee] = 1.0f;
    else if (ky == prefix) {
      u32 p = atomicAdd(&scal[2], 1u);
      tie[p] = (u32)ee;
    }
  }
  __syncthreads();
  int tc = (int)scal[2];
  for (int i = tid; i < tc; i += 1024) {
    u32 ei = tie[i];
    int rank = 0, j = 0;
    for (; j + 8 <= tc; j += 8) {
      u32 a0 = tie[j], a1 = tie[j + 1], a2 = tie[j + 2], a3 = tie[j + 3];
      u32 a4 = tie[j + 4], a5 = tie[j + 5], a6 = tie[j + 6], a7 = tie[j + 7];
      rank += (int)(a0 < ei) + (int)(a1 < ei) + (int)(a2 < ei) + (int)(a3 < ei)
            + (int)(a4 < ei) + (int)(a5 < ei) + (int)(a6 < ei) + (int)(a7 < ei);
    }
    for (; j < tc; ++j) rank += (int)(tie[j] < ei);
    if (rank < (int)need) out[obase + ei] = 1.0f;
  }
}

extern "C" void kernel_launch(void* const* d_in, const int* in_sizes, int n_in,
                              void* d_out, int out_size, void* d_ws, size_t ws_size,
                              hipStream_t stream) {
  if (ws_size < (size_t)WS_NEED) return;
  const float* x = (const float*)d_in[0];
  float* out = (float*)d_out;
  char* ws = (char*)d_ws;
  u32* mm = (u32*)(ws + WS_MM);
  float* corr = (float*)(ws + WS_CORR);
  u32* wcnt = (u32*)(ws + WS_WCNT);
  float* mag = (float*)(ws + WS_MAG);
  u32* mmpart = (u32*)(ws + WS_MMPART);   // overlaid on mag region
  u32* histc = (u32*)(ws + WS_HISTC);     // overlaid on mag region
  u64* cand = (u64*)d_out;                // consumed by k_merge_graph

  hipLaunchKernelGGL(k_minmax_pass, dim3(2048), dim3(256), 0, stream, x, mmpart);
  hipLaunchKernelGGL(k_mm_reduce, dim3(4), dim3(256), 0, stream, mmpart, mm);
  hipLaunchKernelGGL(k_hist_pass, dim3(2048), dim3(256), 0, stream, x, mm, histc);
  hipLaunchKernelGGL(k_corr, dim3(4), dim3(256), 0, stream, histc, corr);
  hipLaunchKernelGGL(k_mag_all, dim3(256), dim3(256), 0, stream, x, corr, mag);
  hipLaunchKernelGGL(k_top64_local, dim3(448), dim3(64), 0, stream, mag, cand, wcnt);
  hipLaunchKernelGGL(k_merge_graph, dim3(28), dim3(1024), 0, stream, cand, wcnt, out);
}

// Round 17
// 171.625 us; speedup vs baseline: 1.4731x; 1.0765x over previous
//
#include <hip/hip_runtime.h>
#include <stdint.h>

// ============================================================================
// Motion_Relation_Mining — bit-exact replication of the JAX (CPU) reference.
//
// FROZEN (verified passing R0-R16, absmax 0.0): all f32 op sequences,
// NAN_POLICY_A, FMA-tanh, sequential reduce orders, selection key
// (enc(value)<<32)|~idx i.e. (value desc, index asc).
//
// R2: two-stage reductions replaced contended global atomics.
// R3: k_corr parallelized (scratch -> LDS, logs 100-wide).
// R4 (FAILED): ballot match-any — unroll spilled enc[] to scratch.
// R8: block-wide bitwise threshold search — barrier convoy (97us).
// R9: wave-autonomous threshold search (shfl-only, zero barriers).
// R10: k_mag_all (x read once), non-atomic hist partials, fused corr.
// R11 (FAILED): fusing top64 into the 28-block kernel throttled it.
// R12-R16: 448x64 top64 + 28-block merge_graph; radix-169 replicated bins
//      + shfl suffix scan; phase-2 rank merge -> radix select (184.7us).
// R17: GAP EXPERIMENT — 7 -> 5 kernels. (a) mm_reduce folded into
//      k_hist_pass (redundant 48KB L2-hot reduce/block; order-free ->
//      bit-identical). (b) k_mag_all + k_top64_local fused as k_magtop:
//      each of 448 blocks computes its own 16-row mag stripe (FROZEN
//      c-chain), stages in LDS, 4 waves run the 1024-element threshold
//      search (superset proof holds for any subset). Kills the mag HBM
//      round-trip; x re-reads are L3-resident. Candidates: 64 ranges x
//      128/bf in ws; merge wbase widened to 64, candk to 4096.
// ============================================================================

typedef unsigned int u32;
typedef unsigned long long u64;

// sizes
#define BB 4
#define TT 8
#define CC 16
#define HWN 65536              // H*W
#define NF 7
#define FRAME 1048576LL        // C*H*W
#define NELF 7340032.0f        // nf*C*H*W per batch (exact in f32)
#define NPAIR 28
#define SEG 65536

// ws layout (bytes)
#define WS_CORR 128            // float[4]
#define WS_WCNT 144            // u32[28*64] per-wave candidate counts (7168 B)
#define WS_MMPART 16384        // u32[2048][6] = 48 KiB (minmax partials)
#define WS_HISTC  (16384 + 65536 + 2097152)   // u32[2048][300] = 2.4 MiB
#define WS_CAND   (16384 + 65536)             // u64[28][8192] = 1.75 MiB
#define WS_NEED (16384 + 28LL*65536*4)

__device__ __forceinline__ u32 encf(float f) {
  u32 u = __float_as_uint(f);
  return (u & 0x80000000u) ? ~u : (u | 0x80000000u);
}
__device__ __forceinline__ float decf(u32 e) {
  u32 u = (e & 0x80000000u) ? (e ^ 0x80000000u) : ~e;
  return __uint_as_float(u);
}

// ---- single pass over frames: per-batch min/max of x_t, x_t1, x_t*x_t1.
// float4 loads; min/max order-free; product elementwise -> exact.
__global__ void k_minmax_pass(const float* __restrict__ x, u32* __restrict__ part) {
  const int blk = blockIdx.x;            // 2048 blocks: 512 per batch
  const int b = blk >> 9;
  const long long w0 = (long long)(blk & 511) * 2048;
  const int tid = threadIdx.x;
  u32 mn0 = 0xFFFFFFFFu, mx0 = 0u, mn1 = 0xFFFFFFFFu, mx1 = 0u,
      mnp = 0xFFFFFFFFu, mxp = 0u;
  float4 pv0, pv1;
  for (int t = 0; t < 8; ++t) {
    const float4* fp = (const float4*)(x + ((long long)(b * TT + t)) * FRAME + w0);
    float4 v0 = fp[tid];
    float4 v1 = fp[tid + 256];
#define MM_COMP(vc, pc)                                                     \
    {                                                                       \
      u32 ev = encf(vc);                                                    \
      if (t < 7) { mn0 = min(mn0, ev); mx0 = max(mx0, ev); }                \
      if (t > 0) {                                                          \
        mn1 = min(mn1, ev); mx1 = max(mx1, ev);                             \
        u32 ep = encf(__fmul_rn(pc, vc));                                   \
        mnp = min(mnp, ep); mxp = max(mxp, ep);                             \
      }                                                                     \
    }
    MM_COMP(v0.x, pv0.x) MM_COMP(v0.y, pv0.y) MM_COMP(v0.z, pv0.z) MM_COMP(v0.w, pv0.w)
    MM_COMP(v1.x, pv1.x) MM_COMP(v1.y, pv1.y) MM_COMP(v1.z, pv1.z) MM_COMP(v1.w, pv1.w)
#undef MM_COMP
    pv0 = v0; pv1 = v1;
  }
  __shared__ u32 sm[6][256];
  sm[0][tid] = mn0; sm[1][tid] = mx0; sm[2][tid] = mn1;
  sm[3][tid] = mx1; sm[4][tid] = mnp; sm[5][tid] = mxp;
  __syncthreads();
  for (int st = 128; st > 0; st >>= 1) {
    if (tid < st) {
      sm[0][tid] = min(sm[0][tid], sm[0][tid + st]);
      sm[1][tid] = max(sm[1][tid], sm[1][tid + st]);
      sm[2][tid] = min(sm[2][tid], sm[2][tid + st]);
      sm[3][tid] = max(sm[3][tid], sm[3][tid + st]);
      sm[4][tid] = min(sm[4][tid], sm[4][tid + st]);
      sm[5][tid] = max(sm[5][tid], sm[5][tid + st]);
    }
    __syncthreads();
  }
  if (tid == 0) {
    u32* o = part + blk * 6;
    o[0] = sm[0][0]; o[1] = sm[1][0]; o[2] = sm[2][0];
    o[3] = sm[3][0]; o[4] = sm[4][0]; o[5] = sm[5][0];
  }
}

__device__ __forceinline__ int bin_of(float v, float vmin, float den) {
  float tt = __fsub_rn(v, vmin);
  float q = __fdiv_rn(tt, den);
  float z = __fmul_rn(q, 100.0f);
  z = fminf(fmaxf(z, 0.0f), 99.0f);
  return (int)z;
}

// ---- single pass over frames. R17: embeds the mm reduction (each block
// redundantly reduces the 2048x6 partials — 48KB L2-hot, order-free ->
// bit-identical mn/den). Then float4 loads + 32-way lane-replicated LDS
// sub-histograms, flushed NON-atomically to the block's private partial.
__global__ void k_hist_pass(const float* __restrict__ x, const u32* __restrict__ part,
                            u32* __restrict__ histc) {
  __shared__ u32 h[300 * 32];            // reused: first as [6][256] mm scratch
  const int tid = threadIdx.x;
  // phase A: reduce 2048 partials (8 per thread, ILP) -> tree -> mn/den
  {
    u32 a0 = 0xFFFFFFFFu, a1 = 0u, a2 = 0xFFFFFFFFu, a3 = 0u, a4 = 0xFFFFFFFFu, a5 = 0u;
    for (int p = tid; p < 2048; p += 256) {
      const u32* q = part + p * 6;
      a0 = min(a0, q[0]); a1 = max(a1, q[1]);
      a2 = min(a2, q[2]); a3 = max(a3, q[3]);
      a4 = min(a4, q[4]); a5 = max(a5, q[5]);
    }
    h[tid] = a0; h[256 + tid] = a1; h[512 + tid] = a2;
    h[768 + tid] = a3; h[1024 + tid] = a4; h[1280 + tid] = a5;
  }
  __syncthreads();
  for (int st = 128; st > 0; st >>= 1) {
    if (tid < st) {
      h[tid] = min(h[tid], h[tid + st]);
      h[256 + tid] = max(h[256 + tid], h[256 + tid + st]);
      h[512 + tid] = min(h[512 + tid], h[512 + tid + st]);
      h[768 + tid] = max(h[768 + tid], h[768 + tid + st]);
      h[1024 + tid] = min(h[1024 + tid], h[1024 + tid + st]);
      h[1280 + tid] = max(h[1280 + tid], h[1280 + tid + st]);
    }
    __syncthreads();
  }
  const float mn_t = decf(h[0]);
  const float den_t = __fsub_rn(decf(h[256]), decf(h[0]));
  const float mn_1 = decf(h[512]);
  const float den_1 = __fsub_rn(decf(h[768]), decf(h[512]));
  const float mn_p = decf(h[1024]);
  const float den_p = __fsub_rn(decf(h[1280]), decf(h[1024]));
  __syncthreads();                       // all reads done before zeroing
  for (int i = tid; i < 9600; i += 256) h[i] = 0u;
  __syncthreads();
  // phase B: histogram
  const int blk = blockIdx.x;
  const int b = blk >> 9;
  const long long w0 = (long long)(blk & 511) * 2048;
  const int sub = tid & 31;
  float4 pv0, pv1;
  for (int t = 0; t < 8; ++t) {
    const float4* fp = (const float4*)(x + ((long long)(b * TT + t)) * FRAME + w0);
    float4 v0 = fp[tid];
    float4 v1 = fp[tid + 256];
#define HH_COMP(vc, pc)                                                       \
    {                                                                         \
      if (t < 7) atomicAdd(&h[bin_of(vc, mn_t, den_t) * 32 + sub], 1u);       \
      if (t > 0) {                                                            \
        atomicAdd(&h[(100 + bin_of(vc, mn_1, den_1)) * 32 + sub], 1u);        \
        float p = __fmul_rn(pc, vc);                                          \
        atomicAdd(&h[(200 + bin_of(p, mn_p, den_p)) * 32 + sub], 1u);         \
      }                                                                       \
    }
    HH_COMP(v0.x, pv0.x) HH_COMP(v0.y, pv0.y) HH_COMP(v0.z, pv0.z) HH_COMP(v0.w, pv0.w)
    HH_COMP(v1.x, pv1.x) HH_COMP(v1.y, pv1.y) HH_COMP(v1.z, pv1.z) HH_COMP(v1.w, pv1.w)
#undef HH_COMP
    pv0 = v0; pv1 = v1;
  }
  __syncthreads();
  u32* dst = histc + blk * 300;
  for (int i = tid; i < 300; i += 256) {
    u32 s = 0;
#pragma unroll
    for (int c = 0; c < 32; ++c)
      s += h[i * 32 + ((c + i) & 31)];   // rotated: conflict-free banks
    dst[i] = s;                          // non-atomic private partial
  }
}

// Eigen/XLA fast-tanh rational interpolant (FMA form) — FROZEN
__device__ float tanh_emul(float a) {
  const float kClamp = 7.90531110763549805f;
  float xx = fminf(fmaxf(a, -kClamp), kClamp);
  float x2 = __fmul_rn(xx, xx);
  float p = __fmaf_rn(x2, -2.76076847742355e-16f, 2.00018790482477e-13f);
  p = __fmaf_rn(x2, p, -8.60467152213735e-11f);
  p = __fmaf_rn(x2, p, 5.12229709037114e-08f);
  p = __fmaf_rn(x2, p, 1.48572235717979e-05f);
  p = __fmaf_rn(x2, p, 6.37261928875436e-04f);
  p = __fmaf_rn(x2, p, 4.89352455891786e-03f);
  p = __fmul_rn(xx, p);
  float q = __fmaf_rn(x2, 1.19825839466702e-06f, 1.18534705686654e-04f);
  q = __fmaf_rn(x2, q, 2.26843463243900e-03f);
  q = __fmaf_rn(x2, q, 4.89352518554385e-03f);
  float r = __fdiv_rn(p, q);
  if (fabsf(a) < 0.0004f) r = a;
  return r;
}

// ---- per-batch: sum 512 partial histograms (8-way ILP, exact ints),
// then mi/corr with FROZEN sequential chains on thread 0.
__global__ void __launch_bounds__(256) k_corr(const u32* __restrict__ histc,
                                              float* __restrict__ corr) {
  const int b = blockIdx.x;
  const int tid = threadIdx.x;
  __shared__ u32 shist[300];
  __shared__ float shx[100], shx1[100], sterm[100];
  __shared__ float ssum[3];
  for (int i = tid; i < 300; i += 256) {
    const u32* src = histc + (long long)(b * 512) * 300 + i;
    u32 s0 = 0, s1 = 0, s2 = 0, s3 = 0, s4 = 0, s5 = 0, s6 = 0, s7 = 0;
    for (int c = 0; c < 512; c += 8) {   // 8 independent load chains (ILP)
      s0 += src[(c + 0) * 300]; s1 += src[(c + 1) * 300];
      s2 += src[(c + 2) * 300]; s3 += src[(c + 3) * 300];
      s4 += src[(c + 4) * 300]; s5 += src[(c + 5) * 300];
      s6 += src[(c + 6) * 300]; s7 += src[(c + 7) * 300];
    }
    shist[i] = ((s0 + s1) + (s2 + s3)) + ((s4 + s5) + (s6 + s7));
  }
  __syncthreads();
  const u32* HX = shist;
  const u32* HX1 = shist + 100;
  const u32* HJ = shist + 200;
  if (tid < 100) {
    shx[tid] = __fdiv_rn((float)HX[tid], NELF);
    shx1[tid] = __fdiv_rn((float)HX1[tid], NELF);
  }
  __syncthreads();
  if (tid == 0) {
    float Sj = 0.0f;
    for (int i = 0; i < 100; ++i) Sj = __fadd_rn(Sj, (float)HJ[i]);
    float Sx = 0.0f, Sx1 = 0.0f;
    for (int i = 0; i < 100; ++i) Sx = __fadd_rn(Sx, shx[i]);
    for (int i = 0; i < 100; ++i) Sx1 = __fadd_rn(Sx1, shx1[i]);
    ssum[0] = Sj; ssum[1] = Sx; ssum[2] = Sx1;
  }
  __syncthreads();
  if (tid < 100) {
    float Sj = ssum[0], Sx = ssum[1], Sx1 = ssum[2];
    float pj = __fdiv_rn((float)HJ[tid], Sj);
    float px = __fdiv_rn(shx[tid], Sx);
    float px1 = __fdiv_rn(shx1[tid], Sx1);
    float la = (float)log((double)__fadd_rn(pj, 1e-10f));
    float lb = (float)log((double)__fadd_rn(__fmul_rn(px, px1), 1e-10f));
    sterm[tid] = __fmul_rn(pj, __fsub_rn(la, lb));
  }
  __syncthreads();
  if (tid == 0) {
    float mi = 0.0f;
    for (int i = 0; i < 100; ++i) mi = __fadd_rn(mi, sterm[i]);
    float lm = (float)log((double)mi);
    float th = tanh_emul(lm);
    float num = (float)exp(0.8);
    corr[b] = __fdiv_rn(num, th);
  }
}

// ---- R17 fused mag + top-64 superset: 448 blocks (28 bf x 16 w) x 256.
// Block computes mag for its 16-row stripe (frames f,f+1 only — FROZEN
// per-pixel c-chain, identical bits), stages 4096 values in LDS at the
// swizzled s-layout, then each of 4 waves runs the 32-round bitwise
// threshold search on its 1024 elements (shfl-only) and emits enc>=T
// candidates to a private 128-slot range. Superset proof holds per any
// subset: a global-top-64 member has <=63 greater globally, hence <=63
// in its wave's 1024, hence >= wave-T.
__global__ void __launch_bounds__(256) k_magtop(const float* __restrict__ x,
                                                const float* __restrict__ corr,
                                                u64* __restrict__ cand,
                                                u32* __restrict__ wcnt) {
  const int blk = blockIdx.x;        // 448
  const int bf = blk >> 4;
  const int w = blk & 15;
  const int b = bf / NF, f = bf % NF;
  const int tid = threadIdx.x;
  __shared__ float smag[4096];
  const float cb = corr[b];
  const long long hwbase = (long long)w * 4096;   // 16-row stripe
  const float4* x0 = (const float4*)(x + ((long long)(b * TT + f)) * FRAME + hwbase);
  const float4* x1 = (const float4*)(x + ((long long)(b * TT + f + 1)) * FRAME + hwbase);
  float4 acc[4];
#pragma unroll
  for (int k = 0; k < 4; ++k) acc[k] = make_float4(0.f, 0.f, 0.f, 0.f);
  for (int c = 0; c < CC; ++c) {
    const float4* p0 = x0 + (long long)c * 16384;   // HWN/4 stride
    const float4* p1 = x1 + (long long)c * 16384;
    float4 v0[4], v1[4];
#pragma unroll
    for (int k = 0; k < 4; ++k) { v0[k] = p0[k * 256 + tid]; v1[k] = p1[k * 256 + tid]; }
#pragma unroll
    for (int k = 0; k < 4; ++k) {
      acc[k].x = __fadd_rn(acc[k].x, __fadd_rn(__fsub_rn(v1[k].x, v0[k].x), cb));
      acc[k].y = __fadd_rn(acc[k].y, __fadd_rn(__fsub_rn(v1[k].y, v0[k].y), cb));
      acc[k].z = __fadd_rn(acc[k].z, __fadd_rn(__fsub_rn(v1[k].z, v0[k].z), cb));
      acc[k].w = __fadd_rn(acc[k].w, __fadd_rn(__fsub_rn(v1[k].w, v0[k].w), cb));
    }
  }
  // stage at swizzled s-layout (col aligned 4 -> s runs of 4, same g)
#pragma unroll
  for (int k = 0; k < 4; ++k) {
    int li = (k * 256 + tid) * 4;           // local float index (row-major 16x256)
    int r = li >> 8, col = li & 255;
    int gl = ((r >> 3) << 5) + (col >> 3);
    int sl = (gl << 6) + ((r & 7) << 3) + (col & 7);   // divisible by 4
    *(float4*)&smag[sl] = acc[k];
  }
  __syncthreads();
  // wave-autonomous top-64 superset over this wave's 1024 elements
  const int lane = tid & 63, wq = tid >> 6;
  const float4* m4 = (const float4*)&smag[wq * 1024];
  u32 e[16];
#pragma unroll
  for (int k = 0; k < 4; ++k) {
    float4 v = m4[k * 64 + lane];
    e[4 * k + 0] = encf(v.x); e[4 * k + 1] = encf(v.y);
    e[4 * k + 2] = encf(v.z); e[4 * k + 3] = encf(v.w);
  }
  u32 T = 0u;
  for (int bit = 31; bit >= 0; --bit) {
    u32 Tt = T | (1u << bit);
    u32 c = 0;
#pragma unroll
    for (int k = 0; k < 16; ++k) c += (e[k] >= Tt) ? 1u : 0u;
#pragma unroll
    for (int off = 1; off < 64; off <<= 1) c += __shfl_xor(c, off, 64);
    if (c >= 64u) T = Tt;
  }
  const int wid64 = (w << 2) + wq;
  u64* dst = cand + (long long)bf * 8192 + wid64 * 128;
  u32 run = 0;
  const u64 below = (lane == 0) ? 0ull : (~0ull >> (64 - lane));
#pragma unroll
  for (int k = 0; k < 16; ++k) {
    bool cnd = (e[k] >= T);
    u64 mask = __ballot(cnd);
    if (cnd) {
      u32 off = run + (u32)__popcll(mask & below);
      if (off < 128u) {
        int s = (w << 12) + (wq << 10) + ((k >> 2) * 64 + lane) * 4 + (k & 3);
        dst[off] = ((u64)e[k] << 32) | (u64)(0xFFFFFFFFu - (u32)s);
      }
    }
    run += (u32)__popcll(mask);
  }
  if (lane == 0) wcnt[bf * 64 + wid64] = (run < 128u) ? run : 128u;
}

// ---- fused merge + graph (28 blocks x 1024).
// Phase 2: radix-select top-64 on candidate enc (hi-32), fixed-bound 64x64
// rank. Phases 3-5: FROZEN cov/inv/maha/radix-169. R17: 64 candidate
// ranges (wbase scan over 64 counts), candk widened to 4096.
__global__ void __launch_bounds__(1024) k_merge_graph(const u64* __restrict__ cand,
                                                      const u32* __restrict__ wcnt,
                                                      float* __restrict__ out) {
  const int bf = blockIdx.x;
  const int tid = threadIdx.x;
  __shared__ u64 candk[4096];
  __shared__ u64 sel64[64];
  __shared__ u32 wbase[65];
  __shared__ float cy[64], cx[64];
  __shared__ float sinv[4];
  __shared__ u32 keys[4096];
  __shared__ u32 bins[256 * 32];
  __shared__ u32 stot[256];
  __shared__ u32 tie[4096];
  __shared__ u32 scal[4];

  // wave-0 inclusive scan over 64 counts
  if (tid < 64) {
    u32 v = wcnt[bf * 64 + tid];
#pragma unroll
    for (int off = 1; off < 64; off <<= 1) {
      u32 t = __shfl_up(v, off, 64);
      if (tid >= off) v += t;
    }
    wbase[tid + 1] = v;
    if (tid == 0) wbase[0] = 0u;
  }
  __syncthreads();
  // compaction: wave wv handles ranges wv, wv+16, wv+32, wv+48
  {
    int wv = tid >> 6, ln = tid & 63;
    for (int rr = wv; rr < 64; rr += 16) {
      u32 base = wbase[rr], cnt = wbase[rr + 1] - base;
      for (u32 s2 = ln; s2 < cnt; s2 += 64) {
        u32 p = base + s2;
        if (p < 4096u) candk[p] = cand[(long long)bf * 8192 + rr * 128 + s2];
      }
    }
  }
  __syncthreads();
  u32 n = wbase[64];
  if (n > 4096u) n = 4096u;

  // phase 2: radix-select the 64th-largest enc among candidates
  u32 prefix2 = 0u, need2 = 64u;
  for (int pass = 0; pass < 4; ++pass) {
    int shift = 24 - pass * 8;
    for (int i = tid; i < 8192; i += 1024) bins[i] = 0u;
    __syncthreads();
    for (u32 i = tid; i < n; i += 1024) {
      u32 e = (u32)(candk[i] >> 32);
      bool ok = (pass == 0) || ((e >> (shift + 8)) == (prefix2 >> (shift + 8)));
      if (ok) atomicAdd(&bins[(((e >> shift) & 0xFFu) << 5) + (tid & 31)], 1u);
    }
    __syncthreads();
    if (tid < 256) {
      u32 s = 0;
#pragma unroll
      for (int c = 0; c < 32; ++c) s += bins[(tid << 5) + ((c + tid) & 31)];
      stot[tid] = s;
    }
    __syncthreads();
    if (tid < 64) {
      int l = tid;
      u32 t0 = stot[4 * l + 0], t1 = stot[4 * l + 1],
          t2 = stot[4 * l + 2], t3 = stot[4 * l + 3];
      u32 b3 = t3, b2 = t2 + b3, b1 = t1 + b2, b0 = t0 + b1;
      u32 incl = b0;
#pragma unroll
      for (int off = 1; off < 64; off <<= 1) {
        u32 t = __shfl_down(incl, off, 64);
        if (l + off < 64) incl += t;
      }
      u32 excl = incl - b0;
      u32 si0 = b0 + excl, si1 = b1 + excl, si2 = b2 + excl, si3 = b3 + excl;
      if (si0 >= need2 && si1 < need2) { scal[0] = prefix2 | ((u32)(4 * l + 0) << shift); scal[1] = need2 - si1; }
      if (si1 >= need2 && si2 < need2) { scal[0] = prefix2 | ((u32)(4 * l + 1) << shift); scal[1] = need2 - si2; }
      if (si2 >= need2 && si3 < need2) { scal[0] = prefix2 | ((u32)(4 * l + 2) << shift); scal[1] = need2 - si3; }
      if (si3 >= need2 && excl < need2) { scal[0] = prefix2 | ((u32)(4 * l + 3) << shift); scal[1] = need2 - excl; }
    }
    __syncthreads();
    prefix2 = scal[0]; need2 = scal[1];
    __syncthreads();
  }
  if (tid == 0) { scal[2] = 0u; scal[3] = 0u; }
  __syncthreads();
  for (u32 i = tid; i < n; i += 1024) {
    u64 key = candk[i];
    u32 e = (u32)(key >> 32);
    if (e > prefix2) {
      u32 p = atomicAdd(&scal[3], 1u);
      sel64[p] = key;
    } else if (e == prefix2) {
      u32 p = atomicAdd(&scal[2], 1u);
      tie[p] = (u32)(key & 0xFFFFFFFFull);   // ~s (larger = smaller idx)
    }
  }
  __syncthreads();
  {
    int tc2 = (int)scal[2];
    for (int i = tid; i < tc2; i += 1024) {
      u32 mine = tie[i];
      int r = 0, j = 0;
      for (; j + 8 <= tc2; j += 8) {
        u32 a0 = tie[j], a1 = tie[j + 1], a2 = tie[j + 2], a3 = tie[j + 3];
        u32 a4 = tie[j + 4], a5 = tie[j + 5], a6 = tie[j + 6], a7 = tie[j + 7];
        r += (int)(a0 > mine) + (int)(a1 > mine) + (int)(a2 > mine) + (int)(a3 > mine)
           + (int)(a4 > mine) + (int)(a5 > mine) + (int)(a6 > mine) + (int)(a7 > mine);
      }
      for (; j < tc2; ++j) r += (int)(tie[j] > mine);
      if (r < (int)need2) {
        u32 p = atomicAdd(&scal[3], 1u);
        sel64[p] = ((u64)prefix2 << 32) | (u64)mine;
      }
    }
  }
  __syncthreads();
  if (tid < 64) {
    u64 mine = sel64[tid];
    int rank = 0;
#pragma unroll
    for (int j = 0; j < 64; ++j) rank += (sel64[j] > mine) ? 1 : 0;
    int idx = (int)(0xFFFFFFFFu - (u32)(mine & 0xFFFFFFFFull));
    cy[rank] = (float)((idx >> 6) * 8 + 4);
    cx[rank] = (float)((idx & 63) * 8 + 4);
  }
  __syncthreads();

  // mean/cov/inv — FROZEN sequential chains on thread 0
  if (tid == 0) {
    float sy = 0.f, sx = 0.f;
    for (int r = 0; r < 64; ++r) sy = __fadd_rn(sy, cy[r]);
    for (int r = 0; r < 64; ++r) sx = __fadd_rn(sx, cx[r]);
    float my = __fdiv_rn(sy, 64.0f), mx = __fdiv_rn(sx, 64.0f);
    float c00 = 0.f, c01 = 0.f, c11 = 0.f;
    for (int r = 0; r < 64; ++r) {
      float dy = __fsub_rn(cy[r], my);
      float dx = __fsub_rn(cx[r], mx);
      c00 = __fadd_rn(c00, __fmul_rn(dy, dy));
      c01 = __fadd_rn(c01, __fmul_rn(dy, dx));
      c11 = __fadd_rn(c11, __fmul_rn(dx, dx));
    }
    c00 = __fdiv_rn(c00, 63.0f); c01 = __fdiv_rn(c01, 63.0f); c11 = __fdiv_rn(c11, 63.0f);
    c00 = __fadd_rn(c00, 1e-6f); c11 = __fadd_rn(c11, 1e-6f);
    double det = (double)c00 * (double)c11 - (double)c01 * (double)c01;
    sinv[0] = (float)((double)c11 / det);
    sinv[1] = (float)(-(double)c01 / det);
    sinv[2] = sinv[1];
    sinv[3] = (float)((double)c00 / det);
  }
  __syncthreads();

  // maha keys + zero output — FROZEN arithmetic, order-independent
  float i00 = sinv[0], i01 = sinv[1], i10 = sinv[2], i11 = sinv[3];
  long long obase = (long long)bf * 4096;
  for (int ee = tid; ee < 4096; ee += 1024) {
    int q = ee >> 6, r = ee & 63;
    float d0 = __fsub_rn(cy[r], cy[q]);
    float d1 = __fsub_rn(cx[r], cx[q]);
    float v0 = __fadd_rn(__fadd_rn(0.0f, __fmul_rn(d0, i00)), __fmul_rn(d1, i10));
    float v1 = __fadd_rn(__fadd_rn(0.0f, __fmul_rn(d0, i01)), __fmul_rn(d1, i11));
    float p0 = __fmul_rn(v0, d0);
    float p1 = __fmul_rn(v1, d1);
    float s0 = __fsqrt_rn(p0);
    float s1 = __fsqrt_rn(p1);
    float mh = __fadd_rn(__fadd_rn(0.0f, s0), s1);
    u32 key;
    if (mh != mh) key = 0xFFFFFFFFu;   // NaN first (POLICY A, FROZEN)
    else key = encf(-mh);
    keys[ee] = key;
    out[obase + ee] = 0.0f;
  }
  __syncthreads();

  // radix-select top-169: 32-way replicated bins + wave-0 shfl suffix scan
  u32 prefix = 0u, need = 169u;
  for (int pass = 0; pass < 4; ++pass) {
    int shift = 24 - pass * 8;
    if (tid == 0) scal[2] = 0u;
    for (int i = tid; i < 8192; i += 1024) bins[i] = 0u;
    __syncthreads();
    for (int k = 0; k < 4; ++k) {
      u32 ky = keys[tid + (k << 10)];
      bool ok = (pass == 0) || ((ky >> (shift + 8)) == (prefix >> (shift + 8)));
      if (ok) atomicAdd(&bins[(((ky >> shift) & 0xFFu) << 5) + (tid & 31)], 1u);
    }
    __syncthreads();
    if (tid < 256) {
      u32 s = 0;
#pragma unroll
      for (int c = 0; c < 32; ++c) s += bins[(tid << 5) + ((c + tid) & 31)];
      stot[tid] = s;
    }
    __syncthreads();
    if (tid < 64) {
      int l = tid;
      u32 t0 = stot[4 * l + 0], t1 = stot[4 * l + 1],
          t2 = stot[4 * l + 2], t3 = stot[4 * l + 3];
      u32 b3 = t3;
      u32 b2 = t2 + b3;
      u32 b1 = t1 + b2;
      u32 b0 = t0 + b1;
      u32 incl = b0;
#pragma unroll
      for (int off = 1; off < 64; off <<= 1) {
        u32 t = __shfl_down(incl, off, 64);
        if (l + off < 64) incl += t;
      }
      u32 excl = incl - b0;
      u32 si0 = b0 + excl, si1 = b1 + excl, si2 = b2 + excl, si3 = b3 + excl;
      if (si0 >= need && si1 < need) { scal[0] = prefix | ((u32)(4 * l + 0) << shift); scal[1] = need - si1; }
      if (si1 >= need && si2 < need) { scal[0] = prefix | ((u32)(4 * l + 1) << shift); scal[1] = need - si2; }
      if (si2 >= need && si3 < need) { scal[0] = prefix | ((u32)(4 * l + 2) << shift); scal[1] = need - si3; }
      if (si3 >= need && excl < need) { scal[0] = prefix | ((u32)(4 * l + 3) << shift); scal[1] = need - excl; }
    }
    __syncthreads();
    prefix = scal[0]; need = scal[1];
    __syncthreads();
  }
  for (int k = 0; k < 4; ++k) {
    int ee = tid + (k << 10);
    u32 ky = keys[ee];
    if (ky > prefix) out[obase + ee] = 1.0f;
    else if (ky == prefix) {
      u32 p = atomicAdd(&scal[2], 1u);
      tie[p] = (u32)ee;
    }
  }
  __syncthreads();
  int tc = (int)scal[2];
  for (int i = tid; i < tc; i += 1024) {
    u32 ei = tie[i];
    int rank = 0, j = 0;
    for (; j + 8 <= tc; j += 8) {
      u32 a0 = tie[j], a1 = tie[j + 1], a2 = tie[j + 2], a3 = tie[j + 3];
      u32 a4 = tie[j + 4], a5 = tie[j + 5], a6 = tie[j + 6], a7 = tie[j + 7];
      rank += (int)(a0 < ei) + (int)(a1 < ei) + (int)(a2 < ei) + (int)(a3 < ei)
            + (int)(a4 < ei) + (int)(a5 < ei) + (int)(a6 < ei) + (int)(a7 < ei);
    }
    for (; j < tc; ++j) rank += (int)(tie[j] < ei);
    if (rank < (int)need) out[obase + ei] = 1.0f;
  }
}

extern "C" void kernel_launch(void* const* d_in, const int* in_sizes, int n_in,
                              void* d_out, int out_size, void* d_ws, size_t ws_size,
                              hipStream_t stream) {
  if (ws_size < (size_t)WS_NEED) return;
  const float* x = (const float*)d_in[0];
  float* out = (float*)d_out;
  char* ws = (char*)d_ws;
  float* corr = (float*)(ws + WS_CORR);
  u32* wcnt = (u32*)(ws + WS_WCNT);
  u32* mmpart = (u32*)(ws + WS_MMPART);
  u64* cand = (u64*)(ws + WS_CAND);
  u32* histc = (u32*)(ws + WS_HISTC);

  hipLaunchKernelGGL(k_minmax_pass, dim3(2048), dim3(256), 0, stream, x, mmpart);
  hipLaunchKernelGGL(k_hist_pass, dim3(2048), dim3(256), 0, stream, x, mmpart, histc);
  hipLaunchKernelGGL(k_corr, dim3(4), dim3(256), 0, stream, histc, corr);
  hipLaunchKernelGGL(k_magtop, dim3(448), dim3(256), 0, stream, x, corr, cand, wcnt);
  hipLaunchKernelGGL(k_merge_graph, dim3(28), dim3(1024), 0, stream, cand, wcnt, out);
}